// Round 1
// 5947.865 us; speedup vs baseline: 1.4598x; 1.4598x over previous
//
#include <hip/hip_runtime.h>
#include <hip/hip_bf16.h>

typedef unsigned short u16;
typedef float f32x4 __attribute__((ext_vector_type(4)));
typedef short s16x8 __attribute__((ext_vector_type(8)));

// B=4, C=D=60, N=25, H=W=96; HW=9216, S=230400, HW2=2304, S2=57600, DN=1500 (pad 1536)
// Batch-serial pipeline: all per-batch buffers fit in ~225 MB of workspace.
// PF_b rows (180): 0..59 spa_q | 60..119 ang_v | 120..179 fre_v
// CAT_b (bf16): slot = qc*25+n (qc 0..179), inner hw.

__device__ __forceinline__ float b2f(u16 u) {
  union { unsigned int i; float f; } v; v.i = ((unsigned int)u) << 16; return v.f;
}
__device__ __forceinline__ u16 f2b(float f) {
  union { float f; unsigned int i; } v; v.f = f;
  unsigned int i = v.i + 0x7FFFu + ((v.i >> 16) & 1u);  // RNE
  return (u16)(i >> 16);
}

// ---------------- fallback (ws too small): out = x ----------------
__global__ void fallback_copy(const float* __restrict__ x, float* __restrict__ out, size_t n) {
  size_t i = (size_t)blockIdx.x * 256 + threadIdx.x;
  size_t st = (size_t)gridDim.x * 256;
  for (; i < n; i += st) out[i] = x[i];
}

// ---------------- cast x_b -> bf16 (1536,9216), pad rows zeroed ----------------
__global__ __launch_bounds__(256) void cast_x(const float* __restrict__ xb, u16* __restrict__ Xb) {
  size_t e = ((size_t)blockIdx.x * 256 + threadIdx.x) * 4;   // < 14155776
  ushort4 o;
  if (e < 13824000) {
    float4 v = *(const float4*)(xb + e);
    o.x = f2b(v.x); o.y = f2b(v.y); o.z = f2b(v.z); o.w = f2b(v.w);
  } else { o.x = 0; o.y = 0; o.z = 0; o.w = 0; }
  *(ushort4*)(Xb + e) = o;
}

// ---------------- projections (per batch) ----------------
__global__ __launch_bounds__(256) void proj_full(const float* __restrict__ xb,
    const float* __restrict__ Wq, const float* __restrict__ Wang,
    const float* __restrict__ Wfre, u16* __restrict__ PF) {
  int s = blockIdx.x * 256 + threadIdx.x;      // 0..230399
  const float* xs = xb + s;
  float xr[60];
#pragma unroll
  for (int c = 0; c < 60; ++c) xr[c] = xs[(size_t)c * 230400];
  u16* ob = PF + s;
  for (int r = 0; r < 60; ++r) {                 // spa_q
    const float* w = Wq + r * 60; float a = 0.f;
#pragma unroll
    for (int c = 0; c < 60; ++c) a += w[c] * xr[c];
    ob[(size_t)r * 230400] = f2b(a);
  }
  for (int r = 0; r < 60; ++r) {                 // ang_v = w_ang rows 120..179
    const float* w = Wang + (120 + r) * 60; float a = 0.f;
#pragma unroll
    for (int c = 0; c < 60; ++c) a += w[c] * xr[c];
    ob[(size_t)(60 + r) * 230400] = f2b(a);
  }
  for (int r = 0; r < 60; ++r) {                 // fre_v = w_fre rows 120..179
    const float* w = Wfre + (120 + r) * 60; float a = 0.f;
#pragma unroll
    for (int c = 0; c < 60; ++c) a += w[c] * xr[c];
    ob[(size_t)(120 + r) * 230400] = f2b(a);
  }
}

__global__ __launch_bounds__(256) void proj_sub(const float* __restrict__ xb,
    const float* __restrict__ Wkv, u16* __restrict__ PS) {
  int s2 = blockIdx.x * 256 + threadIdx.x;     // 0..57599
  int nn = s2 / 2304; int rem = s2 - nn * 2304;
  int hy = rem / 48;  int hx = rem - hy * 48;
  const float* xs = xb + (size_t)nn * 9216 + hy * 192 + hx * 2;
  float xr[60];
#pragma unroll
  for (int c = 0; c < 60; ++c) xr[c] = xs[(size_t)c * 230400];
  u16* ob = PS + s2;
  for (int r = 0; r < 120; ++r) {
    const float* w = Wkv + r * 60; float a = 0.f;
#pragma unroll
    for (int c = 0; c < 60; ++c) a += w[c] * xr[c];
    ob[(size_t)r * 57600] = f2b(a);
  }
}

// ---------------- normalize (over f=1500) + transpose to (site, 1536) ----------------
__global__ __launch_bounds__(256) void norm_transpose(const u16* __restrict__ inb,
    u16* __restrict__ outb, int S) {
  __shared__ float red[256];
  __shared__ float rinv[64];
  __shared__ float Ts[64 * 65];
  int s0 = blockIdx.x * 64;
  int t = threadIdx.x; int sl = t & 63; int g = t >> 6;
  float ss = 0.f;
  for (int f = g; f < 1500; f += 4) {
    float v = b2f(inb[(size_t)f * S + s0 + sl]);
    ss += v * v;
  }
  red[t] = ss; __syncthreads();
  if (t < 64) {
    float tot = red[t] + red[t + 64] + red[t + 128] + red[t + 192];
    rinv[t] = 1.f / fmaxf(sqrtf(tot), 1e-12f);
  }
  __syncthreads();
  for (int f0 = 0; f0 < 1536; f0 += 64) {
    for (int e = t; e < 4096; e += 256) {
      int fr = e >> 6, sc = e & 63; int f = f0 + fr;
      Ts[fr * 65 + sc] = (f < 1500) ? b2f(inb[(size_t)f * S + s0 + sc]) : 0.f;
    }
    __syncthreads();
    for (int sr = g; sr < 64; sr += 4) {
      float v = Ts[sl * 65 + sr] * rinv[sr];
      outb[(size_t)(s0 + sr) * 1536 + f0 + sl] = f2b(v);
    }
    __syncthreads();
  }
}

// ---------------- bf16 MFMA GEMM: C[M,N] = A[M,K] * BT[N,K]^T (per batch) ----------------
// EPI 0: fp32 row-major. EPI 2: bf16 col-major (col*M+row), col<1500 only.
template<int M, int N, int K, int EPI>
__global__ __launch_bounds__(256) void gemm_bt(const u16* __restrict__ A,
    const u16* __restrict__ BT, void* __restrict__ C) {
  __shared__ __align__(16) u16 As[128 * 40];
  __shared__ __align__(16) u16 Bs[128 * 40];
  const int tid = threadIdx.x;
  const int bm = blockIdx.x, bn = blockIdx.y;
  const int lane = tid & 63;
  const int wv = tid >> 6;
  const int wm = (wv >> 1) * 64, wn = (wv & 1) * 64;
  const int lm = lane & 15, lq = lane >> 4;
  f32x4 z = {0.f, 0.f, 0.f, 0.f};
  f32x4 acc[4][4];
#pragma unroll
  for (int i = 0; i < 4; ++i)
#pragma unroll
    for (int j = 0; j < 4; ++j) acc[i][j] = z;

  for (int k0 = 0; k0 < K; k0 += 32) {
    __syncthreads();
#pragma unroll
    for (int r = 0; r < 4; ++r) {
      int idx = tid + (r << 8);              // 0..1023
      int row = (idx >> 2) & 127;
      int seg = idx & 3;
      if (r < 2) {
        const uint4* src = (const uint4*)(A + (size_t)(bm * 128 + row) * K + k0 + seg * 8);
        *(uint4*)&As[row * 40 + seg * 8] = *src;
      } else {
        const uint4* src = (const uint4*)(BT + (size_t)(bn * 128 + row) * K + k0 + seg * 8);
        *(uint4*)&Bs[row * 40 + seg * 8] = *src;
      }
    }
    __syncthreads();
    s16x8 af[4], bf[4];
#pragma unroll
    for (int i = 0; i < 4; ++i)
      af[i] = *(const s16x8*)&As[(wm + i * 16 + lm) * 40 + lq * 8];
#pragma unroll
    for (int j = 0; j < 4; ++j)
      bf[j] = *(const s16x8*)&Bs[(wn + j * 16 + lm) * 40 + lq * 8];
#pragma unroll
    for (int i = 0; i < 4; ++i)
#pragma unroll
      for (int j = 0; j < 4; ++j)
        acc[i][j] = __builtin_amdgcn_mfma_f32_16x16x32_bf16(af[i], bf[j], acc[i][j], 0, 0, 0);
  }

#pragma unroll
  for (int i = 0; i < 4; ++i) {
    int row0 = bm * 128 + wm + i * 16 + lq * 4;
#pragma unroll
    for (int j = 0; j < 4; ++j) {
      int col = bn * 128 + wn + j * 16 + lm;
      if (EPI == 0) {
        float* Cb = (float*)C;
#pragma unroll
        for (int r = 0; r < 4; ++r)
          Cb[(size_t)(row0 + r) * N + col] = acc[i][j][r];
      } else {
        if (col < 1500) {
          u16* Cb = (u16*)C;
          uint2 pk;
          pk.x = (unsigned int)f2b(acc[i][j][0]) | ((unsigned int)f2b(acc[i][j][1]) << 16);
          pk.y = (unsigned int)f2b(acc[i][j][2]) | ((unsigned int)f2b(acc[i][j][3]) << 16);
          *(uint2*)&Cb[(size_t)col * M + row0] = pk;
        }
      }
    }
  }
}

// ---------------- row softmax (2304 cols) fp32 -> bf16 ----------------
__global__ __launch_bounds__(256) void softmax_rows(const float* __restrict__ L,
                                                    u16* __restrict__ att) {
  size_t row = blockIdx.x;
  const float* Lr = L + row * 2304;
  u16* ar = att + row * 2304;
  int t = threadIdx.x;
  float v[9]; float mx = -1e30f;
#pragma unroll
  for (int i = 0; i < 9; ++i) { v[i] = Lr[t + i * 256]; mx = fmaxf(mx, v[i]); }
  __shared__ float red[256];
  red[t] = mx; __syncthreads();
  for (int st = 128; st > 0; st >>= 1) { if (t < st) red[t] = fmaxf(red[t], red[t + st]); __syncthreads(); }
  mx = red[0]; __syncthreads();
  float s = 0.f;
#pragma unroll
  for (int i = 0; i < 9; ++i) { v[i] = __expf(v[i] - mx); s += v[i]; }
  red[t] = s; __syncthreads();
  for (int st = 128; st > 0; st >>= 1) { if (t < st) red[t] += red[t + st]; __syncthreads(); }
  float rs = 1.f / red[0];
#pragma unroll
  for (int i = 0; i < 9; ++i) ar[t + i * 256] = f2b(v[i] * rs);
}

// ---------------- angular attention: parallel contraction over G2 ----------------
// dots layout (675 floats): [0..624] dots[ri*25+ci], [625..649] qn, [650..674] kn
__global__ __launch_bounds__(256) void ang_dots(const float* __restrict__ G,
    const float* __restrict__ Ma_g, const float* __restrict__ Mq_g,
    const float* __restrict__ Mk_g, float* __restrict__ dots) {
  int p = blockIdx.x;                 // 0..674, block-uniform branch
  const float* m; int ri, ci;
  if (p < 625)      { m = Ma_g; ri = p / 25; ci = p % 25; }
  else if (p < 650) { m = Mq_g; ri = p - 625; ci = ri; }
  else              { m = Mk_g; ri = p - 650; ci = ri; }
  int t = threadIdx.x;
  float a = 0.f;
  for (int e = t; e < 3600; e += 256) {
    int c = e / 60, cp = e - c * 60;
    a += m[e] * G[(size_t)(c * 25 + ri) * 1536 + cp * 25 + ci];
  }
  __shared__ float red[256];
  red[t] = a; __syncthreads();
  for (int st = 128; st > 0; st >>= 1) { if (t < st) red[t] += red[t + st]; __syncthreads(); }
  if (t == 0) dots[p] = red[0];
}

__global__ __launch_bounds__(64) void ang_finish(const float* __restrict__ dots,
                                                 float* __restrict__ Aatt) {
  int t = threadIdx.x;
  if (t < 25) {
    float rq = 1.f / fmaxf(sqrtf(dots[625 + t]), 1e-12f);
    float l[25], mx = -1e30f;
    for (int j = 0; j < 25; ++j) {
      float rk = 1.f / fmaxf(sqrtf(dots[650 + j]), 1e-12f);
      l[j] = dots[t * 25 + j] * rq * rk;
      mx = fmaxf(mx, l[j]);
    }
    float s = 0.f;
    for (int j = 0; j < 25; ++j) { l[j] = __expf(l[j] - mx); s += l[j]; }
    float rs = 1.f / s;
    for (int j = 0; j < 25; ++j) Aatt[t * 25 + j] = l[j] * rs;
  }
}

// ---------------- frequency attention: parallel Gs, then small finish ----------------
__global__ __launch_bounds__(256) void fre_gs(const float* __restrict__ G,
                                              float* __restrict__ Gs) {
  int e = blockIdx.x * 256 + threadIdx.x;   // 0..3599
  if (e >= 3600) return;
  int c = e / 60, cp = e - c * 60;
  const float* base = G + (size_t)(c * 25) * 1536 + cp * 25;
  float a = 0.f;
#pragma unroll
  for (int n = 0; n < 25; ++n) a += base[(size_t)n * 1537];
  Gs[e] = a;
}

__global__ __launch_bounds__(256) void fre_finish(const float* __restrict__ Gs_g,
    const float* __restrict__ Wfre, float* __restrict__ Fatt) {
  __shared__ float Gs[3600], T1q[3600], T1k[3600];
  __shared__ float qn[60], kn[60];
  int t = threadIdx.x;
  for (int e = t; e < 3600; e += 256) Gs[e] = Gs_g[e];
  __syncthreads();
  for (int e = t; e < 3600; e += 256) {       // T1q = Wfq*Gs, T1k = Wfk*Gs
    int u = e / 60, cp = e % 60;
    const float* wq = Wfre + u * 60;
    const float* wk = Wfre + 3600 + u * 60;
    float aq = 0.f, ak = 0.f;
    for (int c = 0; c < 60; ++c) { float g = Gs[c * 60 + cp]; aq += wq[c] * g; ak += wk[c] * g; }
    T1q[e] = aq; T1k[e] = ak;
  }
  __syncthreads();
  for (int e = t; e < 3600; e += 256) {       // dots (reuse Gs)
    int u = e / 60, v = e % 60;
    const float* wk = Wfre + 3600 + v * 60;
    float a = 0.f;
    for (int cp = 0; cp < 60; ++cp) a += T1q[u * 60 + cp] * wk[cp];
    Gs[e] = a;
  }
  for (int u = t; u < 60; u += 256) {
    const float* wq = Wfre + u * 60;
    const float* wk = Wfre + 3600 + u * 60;
    float aq = 0.f, ak = 0.f;
    for (int cp = 0; cp < 60; ++cp) { aq += T1q[u * 60 + cp] * wq[cp]; ak += T1k[u * 60 + cp] * wk[cp]; }
    qn[u] = aq; kn[u] = ak;
  }
  __syncthreads();
  if (t < 60) {
    float rq = 1.f / fmaxf(sqrtf(qn[t]), 1e-12f);
    float l[60], mx = -1e30f;
    for (int v = 0; v < 60; ++v) {
      float rk = 1.f / fmaxf(sqrtf(kn[v]), 1e-12f);
      l[v] = Gs[t * 60 + v] * rq * rk;
      mx = fmaxf(mx, l[v]);
    }
    float s = 0.f;
    for (int v = 0; v < 60; ++v) { l[v] = __expf(l[v] - mx); s += l[v]; }
    float rs = 1.f / s;
    for (int v = 0; v < 60; ++v) Fatt[t * 60 + v] = l[v] * rs;
  }
}

// ---------------- a_fea / f_fea -> CAT (bf16, per batch) ----------------
__global__ __launch_bounds__(256) void a_fea(const u16* __restrict__ PF,
    const float* __restrict__ Aatt, u16* __restrict__ CAT) {
  int hw = blockIdx.x * 256 + threadIdx.x;
  int dd = blockIdx.y;
  const u16* V = PF + ((size_t)(60 + dd)) * 230400 + hw;
  float v[25];
#pragma unroll
  for (int j = 0; j < 25; ++j) v[j] = b2f(V[(size_t)j * 9216]);
  u16* ob = CAT + (size_t)(1500 + dd * 25) * 9216 + hw;
  for (int i = 0; i < 25; ++i) {
    float a = 0.f;
#pragma unroll
    for (int j = 0; j < 25; ++j) a += Aatt[i * 25 + j] * v[j];
    ob[(size_t)i * 9216] = f2b(a);
  }
}

__global__ __launch_bounds__(256) void f_fea(const u16* __restrict__ PF,
    const float* __restrict__ Fatt, u16* __restrict__ CAT) {
  int s = blockIdx.x * 256 + threadIdx.x;
  const u16* V = PF + (size_t)120 * 230400 + s;
  float v[60];
#pragma unroll
  for (int u = 0; u < 60; ++u) v[u] = b2f(V[(size_t)u * 230400]);
  u16* ob = CAT + (size_t)27648000 + s;
  for (int u = 0; u < 60; ++u) {
    float a = 0.f;
#pragma unroll
    for (int vv = 0; vv < 60; ++vv) a += Fatt[u * 60 + vv] * v[vv];
    ob[(size_t)u * 230400] = f2b(a);
  }
}

// ---------------- precompute small weight products (once) ----------------
__global__ void precompute(const float* __restrict__ W1, const float* __restrict__ W2,
    const float* __restrict__ gamma, const float* __restrict__ beta,
    const float* __restrict__ Wang,
    float* __restrict__ Avec, float* __restrict__ Btvec,
    float* __restrict__ W1T, float* __restrict__ W2T,
    float* __restrict__ Ma, float* __restrict__ Mq, float* __restrict__ Mk) {
  int t = threadIdx.x;
  for (int e = t; e < 10800; e += 256) { int q = e / 60, j = e % 60; W1T[e] = W1[j * 180 + q]; }
  for (int e = t; e < 3600;  e += 256) { int j = e / 60, k = e % 60; W2T[e] = W2[k * 60 + j]; }
  for (int e = t; e < 3600; e += 256) {
    int c = e / 60, cp = e % 60;
    const float* Waq = Wang;            // rows 0..59
    const float* Wak = Wang + 3600;     // rows 60..119
    float ma = 0.f, mq = 0.f, mk = 0.f;
    for (int d = 0; d < 60; ++d) {
      float q = Waq[d * 60 + c], qp = Waq[d * 60 + cp];
      float k = Wak[d * 60 + c], kp = Wak[d * 60 + cp];
      ma += q * kp; mq += q * qp; mk += k * kp;
    }
    Ma[e] = ma; Mq[e] = mq; Mk[e] = mk;
  }
  if (t < 60) {
    float a = 0.f, bt = 0.f;
    for (int q = 0; q < 180; ++q) { a += gamma[q] * W1[t * 180 + q]; bt += beta[q] * W1[t * 180 + q]; }
    Avec[t] = a; Btvec[t] = bt;
  }
}

// ---------------- fused LayerNorm + MLP + residual (per batch) ----------------
__global__ __launch_bounds__(256) void fuse_ln_mlp(const u16* __restrict__ CAT,
    const float* __restrict__ xb, const float* __restrict__ gamma,
    const float* __restrict__ W1T, const float* __restrict__ W2T,
    const float* __restrict__ Avec, const float* __restrict__ Btvec,
    float* __restrict__ outb) {
  int s = blockIdx.x * 256 + threadIdx.x;
  const u16* cb = CAT + s;
  float S1[60];
#pragma unroll
  for (int j = 0; j < 60; ++j) S1[j] = 0.f;
  float sum = 0.f, sq = 0.f;
  for (int q = 0; q < 180; ++q) {
    float val = b2f(cb[(size_t)q * 230400]);
    sum += val; sq += val * val;
    float u = val * gamma[q];
    const float* w = W1T + q * 60;
#pragma unroll
    for (int j = 0; j < 60; ++j) S1[j] += u * w[j];
  }
  float mu = sum * (1.f / 180.f);
  float var = sq * (1.f / 180.f) - mu * mu;
  float inv = rsqrtf(var + 1e-5f);
  float y2[60];
#pragma unroll
  for (int k = 0; k < 60; ++k) y2[k] = 0.f;
  for (int j = 0; j < 60; ++j) {
    float y1 = inv * (S1[j] - mu * Avec[j]) + Btvec[j];
    y1 = fmaxf(y1, 0.f);
    const float* w = W2T + j * 60;
#pragma unroll
    for (int k = 0; k < 60; ++k) y2[k] += y1 * w[k];
  }
  const float* xs = xb + s;
  float* ob = outb + s;
#pragma unroll
  for (int k = 0; k < 60; ++k) ob[(size_t)k * 230400] = y2[k] + xs[(size_t)k * 230400];
}

// ---------------- launch ----------------
extern "C" void kernel_launch(void* const* d_in, const int* in_sizes, int n_in,
                              void* d_out, int out_size, void* d_ws, size_t ws_size,
                              hipStream_t stream) {
  const float* x        = (const float*)d_in[0];
  const float* w_spa_q  = (const float*)d_in[1];
  const float* w_spa_kv = (const float*)d_in[2];
  const float* w_ang    = (const float*)d_in[3];
  const float* w_fre    = (const float*)d_in[4];
  const float* ln_gamma = (const float*)d_in[5];
  const float* ln_beta  = (const float*)d_in[6];
  const float* w_mlp1   = (const float*)d_in[7];
  const float* w_mlp2   = (const float*)d_in[8];
  float* out = (float*)d_out;
  (void)in_sizes; (void)n_in; (void)out_size;

  // -------- workspace plan: three overlapping regions, peak ~224.6 MB --------
  char* ws = (char*)d_ws;
  const size_t A1 = 0;                       // U1: PF_b | PS_b
  const size_t A1_PS = 82944256;             // PF_b = 82,944,000 B
  const size_t A2 = 96934656;                // U2: G2_b -> sqn_b+skn_b -> att_b (42,467,328 B)
  const size_t A3 = 139401984;               // U3: Xb_b -> L_b fp32 -> CAT_b bf16 (84,934,656 B)
  size_t off = 224336640;                    // smalls
  auto alloc = [&](size_t bytes) -> void* {
    void* p = ws + off; off = (off + bytes + 255) & ~(size_t)255; return p;
  };
  float* Aatt  = (float*)alloc(4 * 625 * 4);    // 4 batches x 625 floats
  float* Fatt  = (float*)alloc(4 * 3600 * 4);   // 4 batches x 3600 floats
  float* Adots = (float*)alloc(4 * 675 * 4);    // 4 batches x 675 floats (dots|qn|kn)
  float* Gsg   = (float*)alloc(4 * 3600 * 4);   // 4 batches x 3600 floats (fre Gram-sum)
  float* Avec  = (float*)alloc(240);
  float* Btvec = (float*)alloc(240);
  float* W1T   = (float*)alloc(43200);
  float* W2T   = (float*)alloc(14400);
  float* Ma    = (float*)alloc(14400);
  float* Mq    = (float*)alloc(14400);
  float* Mk    = (float*)alloc(14400);

  if (off > ws_size) {  // graceful fallback: out = x (diagnosable, no fault)
    fallback_copy<<<4096, 256, 0, stream>>>(x, out, (size_t)55296000);
    return;
  }

  u16*   PF  = (u16*)(ws + A1);
  u16*   PS  = (u16*)(ws + A1_PS);
  float* G2  = (float*)(ws + A2);            //  9,437,184 B
  u16*   sqn = (u16*)(ws + A2);              // 28,311,552 B
  u16*   skn = (u16*)(ws + A2 + 28311552);   //  7,077,888 B
  u16*   att = (u16*)(ws + A2);              // 42,467,328 B
  u16*   Xb  = (u16*)(ws + A3);              // 28,311,552 B
  float* L   = (float*)(ws + A3);            // 84,934,656 B
  u16*   CAT = (u16*)(ws + A3);              // 82,944,000 B

  precompute<<<1, 256, 0, stream>>>(w_mlp1, w_mlp2, ln_gamma, ln_beta, w_ang,
                                    Avec, Btvec, W1T, W2T, Ma, Mq, Mk);

  for (int b = 0; b < 4; ++b) {
    const float* xb = x + (size_t)b * 13824000;
    float* outb = out + (size_t)b * 13824000;

    // --- gram-based angular + frequency attention ---
    cast_x<<<13824, 256, 0, stream>>>(xb, Xb);
    gemm_bt<1536, 1536, 9216, 0><<<dim3(12, 12), 256, 0, stream>>>(Xb, Xb, G2);
    ang_dots<<<675, 256, 0, stream>>>(G2, Ma, Mq, Mk, Adots + b * 675);
    ang_finish<<<1, 64, 0, stream>>>(Adots + b * 675, Aatt + b * 625);
    fre_gs<<<15, 256, 0, stream>>>(G2, Gsg + b * 3600);
    fre_finish<<<1, 256, 0, stream>>>(Gsg + b * 3600, w_fre, Fatt + b * 3600);

    // --- projections ---
    proj_full<<<900, 256, 0, stream>>>(xb, w_spa_q, w_ang, w_fre, PF);
    proj_sub<<<225, 256, 0, stream>>>(xb, w_spa_kv, PS);

    // --- spatial attention (sqn/skn overwrite G2; Xb dead) ---
    norm_transpose<<<144, 256, 0, stream>>>(PF, sqn, 9216);
    norm_transpose<<<36, 256, 0, stream>>>(PS, skn, 2304);
    gemm_bt<9216, 2304, 1536, 0><<<dim3(72, 18), 256, 0, stream>>>(sqn, skn, L);
    softmax_rows<<<9216, 256, 0, stream>>>(L, att);   // att overwrites sqn/skn (dead)
    gemm_bt<9216, 1536, 2304, 2><<<dim3(72, 12), 256, 0, stream>>>(att, PS + 3456000, CAT);

    // --- small attention features ---
    a_fea<<<dim3(36, 60), 256, 0, stream>>>(PF, Aatt + b * 625, CAT);
    f_fea<<<900, 256, 0, stream>>>(PF, Fatt + b * 3600, CAT);

    // --- LN + MLP + residual ---
    fuse_ln_mlp<<<900, 256, 0, stream>>>(CAT, xb, ln_gamma, W1T, W2T, Avec, Btvec, outb);
  }
}

// Round 2
// 5546.861 us; speedup vs baseline: 1.5654x; 1.0723x over previous
//
#include <hip/hip_runtime.h>
#include <hip/hip_bf16.h>

typedef unsigned short u16;
typedef float f32x4 __attribute__((ext_vector_type(4)));
typedef short s16x8 __attribute__((ext_vector_type(8)));

// B=4, C=D=60, N=25, H=W=96; HW=9216, S=230400, HW2=2304, S2=57600, DN=1500 (pad 1536)
// Batch-serial pipeline: all per-batch buffers fit in ~225 MB of workspace.
// PF_b rows (180): 0..59 spa_q | 60..119 ang_v | 120..179 fre_v
// CAT_b (bf16): slot = qc*25+n (qc 0..179), inner hw.

__device__ __forceinline__ float b2f(u16 u) {
  union { unsigned int i; float f; } v; v.i = ((unsigned int)u) << 16; return v.f;
}
__device__ __forceinline__ u16 f2b(float f) {
  union { float f; unsigned int i; } v; v.f = f;
  unsigned int i = v.i + 0x7FFFu + ((v.i >> 16) & 1u);  // RNE
  return (u16)(i >> 16);
}

// ---------------- fallback (ws too small): out = x ----------------
__global__ void fallback_copy(const float* __restrict__ x, float* __restrict__ out, size_t n) {
  size_t i = (size_t)blockIdx.x * 256 + threadIdx.x;
  size_t st = (size_t)gridDim.x * 256;
  for (; i < n; i += st) out[i] = x[i];
}

// ---------------- cast x_b -> bf16 (1536,9216), pad rows zeroed ----------------
__global__ __launch_bounds__(256) void cast_x(const float* __restrict__ xb, u16* __restrict__ Xb) {
  size_t e = ((size_t)blockIdx.x * 256 + threadIdx.x) * 4;   // < 14155776
  ushort4 o;
  if (e < 13824000) {
    float4 v = *(const float4*)(xb + e);
    o.x = f2b(v.x); o.y = f2b(v.y); o.z = f2b(v.z); o.w = f2b(v.w);
  } else { o.x = 0; o.y = 0; o.z = 0; o.w = 0; }
  *(ushort4*)(Xb + e) = o;
}

// ---------------- projections (per batch) ----------------
// grid (900, 3): grp 0 -> spa_q rows (Wq), grp 1 -> ang_v (Wang+120*60), grp 2 -> fre_v (Wfre+120*60)
// 4-row groups: 4 independent FMA chains to hide VALU latency; per-output c-order unchanged.
__global__ __launch_bounds__(256) void proj_full(const float* __restrict__ xb,
    const float* __restrict__ Wq, const float* __restrict__ Wang,
    const float* __restrict__ Wfre, u16* __restrict__ PF) {
  int s = blockIdx.x * 256 + threadIdx.x;      // 0..230399
  int grp = blockIdx.y;                        // 0..2
  const float* W = (grp == 0) ? Wq : ((grp == 1) ? (Wang + 7200) : (Wfre + 7200));
  const float* xs = xb + s;
  float xr[60];
#pragma unroll
  for (int c = 0; c < 60; ++c) xr[c] = xs[(size_t)c * 230400];
  u16* ob = PF + (size_t)grp * 13824000 + s;
  for (int r0 = 0; r0 < 60; r0 += 4) {
    const float* w0 = W + r0 * 60;
    const float* w1 = w0 + 60;
    const float* w2 = w0 + 120;
    const float* w3 = w0 + 180;
    float a0 = 0.f, a1 = 0.f, a2 = 0.f, a3 = 0.f;
#pragma unroll
    for (int c = 0; c < 60; ++c) {
      float xv = xr[c];
      a0 += w0[c] * xv; a1 += w1[c] * xv; a2 += w2[c] * xv; a3 += w3[c] * xv;
    }
    ob[(size_t)(r0    ) * 230400] = f2b(a0);
    ob[(size_t)(r0 + 1) * 230400] = f2b(a1);
    ob[(size_t)(r0 + 2) * 230400] = f2b(a2);
    ob[(size_t)(r0 + 3) * 230400] = f2b(a3);
  }
}

// grid (225, 4): each grp handles 30 of the 120 kv rows; 5-row ILP groups.
__global__ __launch_bounds__(256) void proj_sub(const float* __restrict__ xb,
    const float* __restrict__ Wkv, u16* __restrict__ PS) {
  int s2 = blockIdx.x * 256 + threadIdx.x;     // 0..57599
  int grp = blockIdx.y;                        // 0..3
  int nn = s2 / 2304; int rem = s2 - nn * 2304;
  int hy = rem / 48;  int hx = rem - hy * 48;
  const float* xs = xb + (size_t)nn * 9216 + hy * 192 + hx * 2;
  float xr[60];
#pragma unroll
  for (int c = 0; c < 60; ++c) xr[c] = xs[(size_t)c * 230400];
  u16* ob = PS + (size_t)grp * 1728000 + s2;   // 30*57600
  const float* Wg = Wkv + grp * 1800;          // 30*60
  for (int r0 = 0; r0 < 30; r0 += 5) {
    const float* w0 = Wg + r0 * 60;
    const float* w1 = w0 + 60;
    const float* w2 = w0 + 120;
    const float* w3 = w0 + 180;
    const float* w4 = w0 + 240;
    float a0 = 0.f, a1 = 0.f, a2 = 0.f, a3 = 0.f, a4 = 0.f;
#pragma unroll
    for (int c = 0; c < 60; ++c) {
      float xv = xr[c];
      a0 += w0[c] * xv; a1 += w1[c] * xv; a2 += w2[c] * xv;
      a3 += w3[c] * xv; a4 += w4[c] * xv;
    }
    ob[(size_t)(r0    ) * 57600] = f2b(a0);
    ob[(size_t)(r0 + 1) * 57600] = f2b(a1);
    ob[(size_t)(r0 + 2) * 57600] = f2b(a2);
    ob[(size_t)(r0 + 3) * 57600] = f2b(a3);
    ob[(size_t)(r0 + 4) * 57600] = f2b(a4);
  }
}

// ---------------- normalize (over f=1500) + transpose to (site, 1536) ----------------
__global__ __launch_bounds__(256) void norm_transpose(const u16* __restrict__ inb,
    u16* __restrict__ outb, int S) {
  __shared__ float red[256];
  __shared__ float rinv[64];
  __shared__ float Ts[64 * 65];
  int s0 = blockIdx.x * 64;
  int t = threadIdx.x; int sl = t & 63; int g = t >> 6;
  float ss = 0.f;
  for (int f = g; f < 1500; f += 4) {
    float v = b2f(inb[(size_t)f * S + s0 + sl]);
    ss += v * v;
  }
  red[t] = ss; __syncthreads();
  if (t < 64) {
    float tot = red[t] + red[t + 64] + red[t + 128] + red[t + 192];
    rinv[t] = 1.f / fmaxf(sqrtf(tot), 1e-12f);
  }
  __syncthreads();
  for (int f0 = 0; f0 < 1536; f0 += 64) {
    for (int e = t; e < 4096; e += 256) {
      int fr = e >> 6, sc = e & 63; int f = f0 + fr;
      Ts[fr * 65 + sc] = (f < 1500) ? b2f(inb[(size_t)f * S + s0 + sc]) : 0.f;
    }
    __syncthreads();
    for (int sr = g; sr < 64; sr += 4) {
      float v = Ts[sl * 65 + sr] * rinv[sr];
      outb[(size_t)(s0 + sr) * 1536 + f0 + sl] = f2b(v);
    }
    __syncthreads();
  }
}

// ---------------- bf16 MFMA GEMM: C[M,N] = A[M,K] * BT[N,K]^T (per batch) ----------------
// EPI 0: fp32 row-major. EPI 2: bf16 col-major (col*M+row), col<1500 only.
template<int M, int N, int K, int EPI>
__global__ __launch_bounds__(256) void gemm_bt(const u16* __restrict__ A,
    const u16* __restrict__ BT, void* __restrict__ C) {
  __shared__ __align__(16) u16 As[128 * 40];
  __shared__ __align__(16) u16 Bs[128 * 40];
  const int tid = threadIdx.x;
  const int bm = blockIdx.x, bn = blockIdx.y;
  const int lane = tid & 63;
  const int wv = tid >> 6;
  const int wm = (wv >> 1) * 64, wn = (wv & 1) * 64;
  const int lm = lane & 15, lq = lane >> 4;
  f32x4 z = {0.f, 0.f, 0.f, 0.f};
  f32x4 acc[4][4];
#pragma unroll
  for (int i = 0; i < 4; ++i)
#pragma unroll
    for (int j = 0; j < 4; ++j) acc[i][j] = z;

  for (int k0 = 0; k0 < K; k0 += 32) {
    __syncthreads();
#pragma unroll
    for (int r = 0; r < 4; ++r) {
      int idx = tid + (r << 8);              // 0..1023
      int row = (idx >> 2) & 127;
      int seg = idx & 3;
      if (r < 2) {
        const uint4* src = (const uint4*)(A + (size_t)(bm * 128 + row) * K + k0 + seg * 8);
        *(uint4*)&As[row * 40 + seg * 8] = *src;
      } else {
        const uint4* src = (const uint4*)(BT + (size_t)(bn * 128 + row) * K + k0 + seg * 8);
        *(uint4*)&Bs[row * 40 + seg * 8] = *src;
      }
    }
    __syncthreads();
    s16x8 af[4], bf[4];
#pragma unroll
    for (int i = 0; i < 4; ++i)
      af[i] = *(const s16x8*)&As[(wm + i * 16 + lm) * 40 + lq * 8];
#pragma unroll
    for (int j = 0; j < 4; ++j)
      bf[j] = *(const s16x8*)&Bs[(wn + j * 16 + lm) * 40 + lq * 8];
#pragma unroll
    for (int i = 0; i < 4; ++i)
#pragma unroll
      for (int j = 0; j < 4; ++j)
        acc[i][j] = __builtin_amdgcn_mfma_f32_16x16x32_bf16(af[i], bf[j], acc[i][j], 0, 0, 0);
  }

#pragma unroll
  for (int i = 0; i < 4; ++i) {
    int row0 = bm * 128 + wm + i * 16 + lq * 4;
#pragma unroll
    for (int j = 0; j < 4; ++j) {
      int col = bn * 128 + wn + j * 16 + lm;
      if (EPI == 0) {
        float* Cb = (float*)C;
#pragma unroll
        for (int r = 0; r < 4; ++r)
          Cb[(size_t)(row0 + r) * N + col] = acc[i][j][r];
      } else {
        if (col < 1500) {
          u16* Cb = (u16*)C;
          uint2 pk;
          pk.x = (unsigned int)f2b(acc[i][j][0]) | ((unsigned int)f2b(acc[i][j][1]) << 16);
          pk.y = (unsigned int)f2b(acc[i][j][2]) | ((unsigned int)f2b(acc[i][j][3]) << 16);
          *(uint2*)&Cb[(size_t)col * M + row0] = pk;
        }
      }
    }
  }
}

// ---------------- row softmax (2304 cols) fp32 -> bf16 ----------------
__global__ __launch_bounds__(256) void softmax_rows(const float* __restrict__ L,
                                                    u16* __restrict__ att) {
  size_t row = blockIdx.x;
  const float* Lr = L + row * 2304;
  u16* ar = att + row * 2304;
  int t = threadIdx.x;
  float v[9]; float mx = -1e30f;
#pragma unroll
  for (int i = 0; i < 9; ++i) { v[i] = Lr[t + i * 256]; mx = fmaxf(mx, v[i]); }
  __shared__ float red[256];
  red[t] = mx; __syncthreads();
  for (int st = 128; st > 0; st >>= 1) { if (t < st) red[t] = fmaxf(red[t], red[t + st]); __syncthreads(); }
  mx = red[0]; __syncthreads();
  float s = 0.f;
#pragma unroll
  for (int i = 0; i < 9; ++i) { v[i] = __expf(v[i] - mx); s += v[i]; }
  red[t] = s; __syncthreads();
  for (int st = 128; st > 0; st >>= 1) { if (t < st) red[t] += red[t + st]; __syncthreads(); }
  float rs = 1.f / red[0];
#pragma unroll
  for (int i = 0; i < 9; ++i) ar[t + i * 256] = f2b(v[i] * rs);
}

// ---------------- angular attention: parallel contraction over G2 ----------------
// dots layout (675 floats): [0..624] dots[ri*25+ci], [625..649] qn, [650..674] kn
__global__ __launch_bounds__(256) void ang_dots(const float* __restrict__ G,
    const float* __restrict__ Ma_g, const float* __restrict__ Mq_g,
    const float* __restrict__ Mk_g, float* __restrict__ dots) {
  int p = blockIdx.x;                 // 0..674, block-uniform branch
  const float* m; int ri, ci;
  if (p < 625)      { m = Ma_g; ri = p / 25; ci = p % 25; }
  else if (p < 650) { m = Mq_g; ri = p - 625; ci = ri; }
  else              { m = Mk_g; ri = p - 650; ci = ri; }
  int t = threadIdx.x;
  float a = 0.f;
  for (int e = t; e < 3600; e += 256) {
    int c = e / 60, cp = e - c * 60;
    a += m[e] * G[(size_t)(c * 25 + ri) * 1536 + cp * 25 + ci];
  }
  __shared__ float red[256];
  red[t] = a; __syncthreads();
  for (int st = 128; st > 0; st >>= 1) { if (t < st) red[t] += red[t + st]; __syncthreads(); }
  if (t == 0) dots[p] = red[0];
}

__global__ __launch_bounds__(64) void ang_finish(const float* __restrict__ dots,
                                                 float* __restrict__ Aatt) {
  int t = threadIdx.x;
  if (t < 25) {
    float rq = 1.f / fmaxf(sqrtf(dots[625 + t]), 1e-12f);
    float l[25], mx = -1e30f;
    for (int j = 0; j < 25; ++j) {
      float rk = 1.f / fmaxf(sqrtf(dots[650 + j]), 1e-12f);
      l[j] = dots[t * 25 + j] * rq * rk;
      mx = fmaxf(mx, l[j]);
    }
    float s = 0.f;
    for (int j = 0; j < 25; ++j) { l[j] = __expf(l[j] - mx); s += l[j]; }
    float rs = 1.f / s;
    for (int j = 0; j < 25; ++j) Aatt[t * 25 + j] = l[j] * rs;
  }
}

// ---------------- frequency attention: parallel Gs, then small finish ----------------
__global__ __launch_bounds__(256) void fre_gs(const float* __restrict__ G,
                                              float* __restrict__ Gs) {
  int e = blockIdx.x * 256 + threadIdx.x;   // 0..3599
  if (e >= 3600) return;
  int c = e / 60, cp = e - c * 60;
  const float* base = G + (size_t)(c * 25) * 1536 + cp * 25;
  float a = 0.f;
#pragma unroll
  for (int n = 0; n < 25; ++n) a += base[(size_t)n * 1537];
  Gs[e] = a;
}

__global__ __launch_bounds__(256) void fre_finish(const float* __restrict__ Gs_g,
    const float* __restrict__ Wfre, float* __restrict__ Fatt) {
  __shared__ float Gs[3600], T1q[3600], T1k[3600];
  __shared__ float qn[60], kn[60];
  int t = threadIdx.x;
  for (int e = t; e < 3600; e += 256) Gs[e] = Gs_g[e];
  __syncthreads();
  for (int e = t; e < 3600; e += 256) {       // T1q = Wfq*Gs, T1k = Wfk*Gs
    int u = e / 60, cp = e % 60;
    const float* wq = Wfre + u * 60;
    const float* wk = Wfre + 3600 + u * 60;
    float aq = 0.f, ak = 0.f;
    for (int c = 0; c < 60; ++c) { float g = Gs[c * 60 + cp]; aq += wq[c] * g; ak += wk[c] * g; }
    T1q[e] = aq; T1k[e] = ak;
  }
  __syncthreads();
  for (int e = t; e < 3600; e += 256) {       // dots (reuse Gs)
    int u = e / 60, v = e % 60;
    const float* wk = Wfre + 3600 + v * 60;
    float a = 0.f;
    for (int cp = 0; cp < 60; ++cp) a += T1q[u * 60 + cp] * wk[cp];
    Gs[e] = a;
  }
  for (int u = t; u < 60; u += 256) {
    const float* wq = Wfre + u * 60;
    const float* wk = Wfre + 3600 + u * 60;
    float aq = 0.f, ak = 0.f;
    for (int cp = 0; cp < 60; ++cp) { aq += T1q[u * 60 + cp] * wq[cp]; ak += T1k[u * 60 + cp] * wk[cp]; }
    qn[u] = aq; kn[u] = ak;
  }
  __syncthreads();
  if (t < 60) {
    float rq = 1.f / fmaxf(sqrtf(qn[t]), 1e-12f);
    float l[60], mx = -1e30f;
    for (int v = 0; v < 60; ++v) {
      float rk = 1.f / fmaxf(sqrtf(kn[v]), 1e-12f);
      l[v] = Gs[t * 60 + v] * rq * rk;
      mx = fmaxf(mx, l[v]);
    }
    float s = 0.f;
    for (int v = 0; v < 60; ++v) { l[v] = __expf(l[v] - mx); s += l[v]; }
    float rs = 1.f / s;
    for (int v = 0; v < 60; ++v) Fatt[t * 60 + v] = l[v] * rs;
  }
}

// ---------------- a_fea / f_fea -> CAT (bf16, per batch) ----------------
__global__ __launch_bounds__(256) void a_fea(const u16* __restrict__ PF,
    const float* __restrict__ Aatt, u16* __restrict__ CAT) {
  int hw = blockIdx.x * 256 + threadIdx.x;
  int dd = blockIdx.y;
  const u16* V = PF + ((size_t)(60 + dd)) * 230400 + hw;
  float v[25];
#pragma unroll
  for (int j = 0; j < 25; ++j) v[j] = b2f(V[(size_t)j * 9216]);
  u16* ob = CAT + (size_t)(1500 + dd * 25) * 9216 + hw;
  for (int i = 0; i < 25; ++i) {
    float a = 0.f;
#pragma unroll
    for (int j = 0; j < 25; ++j) a += Aatt[i * 25 + j] * v[j];
    ob[(size_t)i * 9216] = f2b(a);
  }
}

__global__ __launch_bounds__(256) void f_fea(const u16* __restrict__ PF,
    const float* __restrict__ Fatt, u16* __restrict__ CAT) {
  int s = blockIdx.x * 256 + threadIdx.x;
  const u16* V = PF + (size_t)120 * 230400 + s;
  float v[60];
#pragma unroll
  for (int u = 0; u < 60; ++u) v[u] = b2f(V[(size_t)u * 230400]);
  u16* ob = CAT + (size_t)27648000 + s;
  for (int u = 0; u < 60; ++u) {
    float a = 0.f;
#pragma unroll
    for (int vv = 0; vv < 60; ++vv) a += Fatt[u * 60 + vv] * v[vv];
    ob[(size_t)u * 230400] = f2b(a);
  }
}

// ---------------- precompute small weight products (once) ----------------
__global__ void precompute(const float* __restrict__ W1, const float* __restrict__ W2,
    const float* __restrict__ gamma, const float* __restrict__ beta,
    const float* __restrict__ Wang,
    float* __restrict__ Avec, float* __restrict__ Btvec,
    float* __restrict__ W1T, float* __restrict__ W2T,
    float* __restrict__ Ma, float* __restrict__ Mq, float* __restrict__ Mk) {
  int t = threadIdx.x;
  for (int e = t; e < 10800; e += 256) { int q = e / 60, j = e % 60; W1T[e] = W1[j * 180 + q]; }
  for (int e = t; e < 3600;  e += 256) { int j = e / 60, k = e % 60; W2T[e] = W2[k * 60 + j]; }
  for (int e = t; e < 3600; e += 256) {
    int c = e / 60, cp = e % 60;
    const float* Waq = Wang;            // rows 0..59
    const float* Wak = Wang + 3600;     // rows 60..119
    float ma = 0.f, mq = 0.f, mk = 0.f;
    for (int d = 0; d < 60; ++d) {
      float q = Waq[d * 60 + c], qp = Waq[d * 60 + cp];
      float k = Wak[d * 60 + c], kp = Wak[d * 60 + cp];
      ma += q * kp; mq += q * qp; mk += k * kp;
    }
    Ma[e] = ma; Mq[e] = mq; Mk[e] = mk;
  }
  if (t < 60) {
    float a = 0.f, bt = 0.f;
    for (int q = 0; q < 180; ++q) { a += gamma[q] * W1[t * 180 + q]; bt += beta[q] * W1[t * 180 + q]; }
    Avec[t] = a; Btvec[t] = bt;
  }
}

// ---------------- fused LayerNorm + MLP + residual (per batch) ----------------
__global__ __launch_bounds__(256) void fuse_ln_mlp(const u16* __restrict__ CAT,
    const float* __restrict__ xb, const float* __restrict__ gamma,
    const float* __restrict__ W1T, const float* __restrict__ W2T,
    const float* __restrict__ Avec, const float* __restrict__ Btvec,
    float* __restrict__ outb) {
  int s = blockIdx.x * 256 + threadIdx.x;
  const u16* cb = CAT + s;
  float S1[60];
#pragma unroll
  for (int j = 0; j < 60; ++j) S1[j] = 0.f;
  float sum = 0.f, sq = 0.f;
  for (int q = 0; q < 180; ++q) {
    float val = b2f(cb[(size_t)q * 230400]);
    sum += val; sq += val * val;
    float u = val * gamma[q];
    const float* w = W1T + q * 60;
#pragma unroll
    for (int j = 0; j < 60; ++j) S1[j] += u * w[j];
  }
  float mu = sum * (1.f / 180.f);
  float var = sq * (1.f / 180.f) - mu * mu;
  float inv = rsqrtf(var + 1e-5f);
  float y2[60];
#pragma unroll
  for (int k = 0; k < 60; ++k) y2[k] = 0.f;
  for (int j = 0; j < 60; ++j) {
    float y1 = inv * (S1[j] - mu * Avec[j]) + Btvec[j];
    y1 = fmaxf(y1, 0.f);
    const float* w = W2T + j * 60;
#pragma unroll
    for (int k = 0; k < 60; ++k) y2[k] += y1 * w[k];
  }
  const float* xs = xb + s;
  float* ob = outb + s;
#pragma unroll
  for (int k = 0; k < 60; ++k) ob[(size_t)k * 230400] = y2[k] + xs[(size_t)k * 230400];
}

// ---------------- launch ----------------
extern "C" void kernel_launch(void* const* d_in, const int* in_sizes, int n_in,
                              void* d_out, int out_size, void* d_ws, size_t ws_size,
                              hipStream_t stream) {
  const float* x        = (const float*)d_in[0];
  const float* w_spa_q  = (const float*)d_in[1];
  const float* w_spa_kv = (const float*)d_in[2];
  const float* w_ang    = (const float*)d_in[3];
  const float* w_fre    = (const float*)d_in[4];
  const float* ln_gamma = (const float*)d_in[5];
  const float* ln_beta  = (const float*)d_in[6];
  const float* w_mlp1   = (const float*)d_in[7];
  const float* w_mlp2   = (const float*)d_in[8];
  float* out = (float*)d_out;
  (void)in_sizes; (void)n_in; (void)out_size;

  // -------- workspace plan: three overlapping regions, peak ~224.6 MB --------
  char* ws = (char*)d_ws;
  const size_t A1 = 0;                       // U1: PF_b | PS_b
  const size_t A1_PS = 82944256;             // PF_b = 82,944,000 B
  const size_t A2 = 96934656;                // U2: G2_b -> sqn_b+skn_b -> att_b (42,467,328 B)
  const size_t A3 = 139401984;               // U3: Xb_b -> L_b fp32 -> CAT_b bf16 (84,934,656 B)
  size_t off = 224336640;                    // smalls
  auto alloc = [&](size_t bytes) -> void* {
    void* p = ws + off; off = (off + bytes + 255) & ~(size_t)255; return p;
  };
  float* Aatt  = (float*)alloc(4 * 625 * 4);    // 4 batches x 625 floats
  float* Fatt  = (float*)alloc(4 * 3600 * 4);   // 4 batches x 3600 floats
  float* Adots = (float*)alloc(4 * 675 * 4);    // 4 batches x 675 floats (dots|qn|kn)
  float* Gsg   = (float*)alloc(4 * 3600 * 4);   // 4 batches x 3600 floats (fre Gram-sum)
  float* Avec  = (float*)alloc(240);
  float* Btvec = (float*)alloc(240);
  float* W1T   = (float*)alloc(43200);
  float* W2T   = (float*)alloc(14400);
  float* Ma    = (float*)alloc(14400);
  float* Mq    = (float*)alloc(14400);
  float* Mk    = (float*)alloc(14400);

  if (off > ws_size) {  // graceful fallback: out = x (diagnosable, no fault)
    fallback_copy<<<4096, 256, 0, stream>>>(x, out, (size_t)55296000);
    return;
  }

  u16*   PF  = (u16*)(ws + A1);
  u16*   PS  = (u16*)(ws + A1_PS);
  float* G2  = (float*)(ws + A2);            //  9,437,184 B
  u16*   sqn = (u16*)(ws + A2);              // 28,311,552 B
  u16*   skn = (u16*)(ws + A2 + 28311552);   //  7,077,888 B
  u16*   att = (u16*)(ws + A2);              // 42,467,328 B
  u16*   Xb  = (u16*)(ws + A3);              // 28,311,552 B
  float* L   = (float*)(ws + A3);            // 84,934,656 B
  u16*   CAT = (u16*)(ws + A3);              // 82,944,000 B

  precompute<<<1, 256, 0, stream>>>(w_mlp1, w_mlp2, ln_gamma, ln_beta, w_ang,
                                    Avec, Btvec, W1T, W2T, Ma, Mq, Mk);

  for (int b = 0; b < 4; ++b) {
    const float* xb = x + (size_t)b * 13824000;
    float* outb = out + (size_t)b * 13824000;

    // --- gram-based angular + frequency attention ---
    cast_x<<<13824, 256, 0, stream>>>(xb, Xb);
    gemm_bt<1536, 1536, 9216, 0><<<dim3(12, 12), 256, 0, stream>>>(Xb, Xb, G2);
    ang_dots<<<675, 256, 0, stream>>>(G2, Ma, Mq, Mk, Adots + b * 675);
    ang_finish<<<1, 64, 0, stream>>>(Adots + b * 675, Aatt + b * 625);
    fre_gs<<<15, 256, 0, stream>>>(G2, Gsg + b * 3600);
    fre_finish<<<1, 256, 0, stream>>>(Gsg + b * 3600, w_fre, Fatt + b * 3600);

    // --- projections ---
    proj_full<<<dim3(900, 3), 256, 0, stream>>>(xb, w_spa_q, w_ang, w_fre, PF);
    proj_sub<<<dim3(225, 4), 256, 0, stream>>>(xb, w_spa_kv, PS);

    // --- spatial attention (sqn/skn overwrite G2; Xb dead) ---
    norm_transpose<<<144, 256, 0, stream>>>(PF, sqn, 9216);
    norm_transpose<<<36, 256, 0, stream>>>(PS, skn, 2304);
    gemm_bt<9216, 2304, 1536, 0><<<dim3(72, 18), 256, 0, stream>>>(sqn, skn, L);
    softmax_rows<<<9216, 256, 0, stream>>>(L, att);   // att overwrites sqn/skn (dead)
    gemm_bt<9216, 1536, 2304, 2><<<dim3(72, 12), 256, 0, stream>>>(att, PS + 3456000, CAT);

    // --- small attention features ---
    a_fea<<<dim3(36, 60), 256, 0, stream>>>(PF, Aatt + b * 625, CAT);
    f_fea<<<900, 256, 0, stream>>>(PF, Fatt + b * 3600, CAT);

    // --- LN + MLP + residual ---
    fuse_ln_mlp<<<900, 256, 0, stream>>>(CAT, xb, ln_gamma, W1T, W2T, Avec, Btvec, outb);
  }
}

// Round 3
// 4225.909 us; speedup vs baseline: 2.0547x; 1.3126x over previous
//
#include <hip/hip_runtime.h>
#include <hip/hip_bf16.h>

typedef unsigned short u16;
typedef float f32x4 __attribute__((ext_vector_type(4)));
typedef short s16x8 __attribute__((ext_vector_type(8)));

// B=4, C=D=60, N=25, H=W=96; HW=9216, S=230400, HW2=2304, S2=57600, DN=1500 (pad 1536)
// Batch-serial pipeline: all per-batch buffers fit in ~225 MB of workspace.
// PF_b rows (180): 0..59 spa_q | 60..119 ang_v | 120..179 fre_v
// CAT_b (bf16): slot = qc*25+n (qc 0..179), inner hw.

__device__ __forceinline__ float b2f(u16 u) {
  union { unsigned int i; float f; } v; v.i = ((unsigned int)u) << 16; return v.f;
}
__device__ __forceinline__ u16 f2b(float f) {
  union { float f; unsigned int i; } v; v.f = f;
  unsigned int i = v.i + 0x7FFFu + ((v.i >> 16) & 1u);  // RNE
  return (u16)(i >> 16);
}

// ---------------- fallback (ws too small): out = x ----------------
__global__ void fallback_copy(const float* __restrict__ x, float* __restrict__ out, size_t n) {
  size_t i = (size_t)blockIdx.x * 256 + threadIdx.x;
  size_t st = (size_t)gridDim.x * 256;
  for (; i < n; i += st) out[i] = x[i];
}

// ---------------- cast x_b -> bf16 (1536,9216), pad rows zeroed ----------------
__global__ __launch_bounds__(256) void cast_x(const float* __restrict__ xb, u16* __restrict__ Xb) {
  size_t e = ((size_t)blockIdx.x * 256 + threadIdx.x) * 4;   // < 14155776
  ushort4 o;
  if (e < 13824000) {
    float4 v = *(const float4*)(xb + e);
    o.x = f2b(v.x); o.y = f2b(v.y); o.z = f2b(v.z); o.w = f2b(v.w);
  } else { o.x = 0; o.y = 0; o.z = 0; o.w = 0; }
  *(ushort4*)(Xb + e) = o;
}

// ---------------- projections (per batch) ----------------
// grid (900, 3): grp 0 -> spa_q rows (Wq), grp 1 -> ang_v (Wang+120*60), grp 2 -> fre_v (Wfre+120*60)
// 4-row groups: 4 independent FMA chains to hide VALU latency; per-output c-order unchanged.
__global__ __launch_bounds__(256) void proj_full(const float* __restrict__ xb,
    const float* __restrict__ Wq, const float* __restrict__ Wang,
    const float* __restrict__ Wfre, u16* __restrict__ PF) {
  int s = blockIdx.x * 256 + threadIdx.x;      // 0..230399
  int grp = blockIdx.y;                        // 0..2
  const float* W = (grp == 0) ? Wq : ((grp == 1) ? (Wang + 7200) : (Wfre + 7200));
  const float* xs = xb + s;
  float xr[60];
#pragma unroll
  for (int c = 0; c < 60; ++c) xr[c] = xs[(size_t)c * 230400];
  u16* ob = PF + (size_t)grp * 13824000 + s;
  for (int r0 = 0; r0 < 60; r0 += 4) {
    const float* w0 = W + r0 * 60;
    const float* w1 = w0 + 60;
    const float* w2 = w0 + 120;
    const float* w3 = w0 + 180;
    float a0 = 0.f, a1 = 0.f, a2 = 0.f, a3 = 0.f;
#pragma unroll
    for (int c = 0; c < 60; ++c) {
      float xv = xr[c];
      a0 += w0[c] * xv; a1 += w1[c] * xv; a2 += w2[c] * xv; a3 += w3[c] * xv;
    }
    ob[(size_t)(r0    ) * 230400] = f2b(a0);
    ob[(size_t)(r0 + 1) * 230400] = f2b(a1);
    ob[(size_t)(r0 + 2) * 230400] = f2b(a2);
    ob[(size_t)(r0 + 3) * 230400] = f2b(a3);
  }
}

// grid (225, 4): each grp handles 30 of the 120 kv rows; 5-row ILP groups.
__global__ __launch_bounds__(256) void proj_sub(const float* __restrict__ xb,
    const float* __restrict__ Wkv, u16* __restrict__ PS) {
  int s2 = blockIdx.x * 256 + threadIdx.x;     // 0..57599
  int grp = blockIdx.y;                        // 0..3
  int nn = s2 / 2304; int rem = s2 - nn * 2304;
  int hy = rem / 48;  int hx = rem - hy * 48;
  const float* xs = xb + (size_t)nn * 9216 + hy * 192 + hx * 2;
  float xr[60];
#pragma unroll
  for (int c = 0; c < 60; ++c) xr[c] = xs[(size_t)c * 230400];
  u16* ob = PS + (size_t)grp * 1728000 + s2;   // 30*57600
  const float* Wg = Wkv + grp * 1800;          // 30*60
  for (int r0 = 0; r0 < 30; r0 += 5) {
    const float* w0 = Wg + r0 * 60;
    const float* w1 = w0 + 60;
    const float* w2 = w0 + 120;
    const float* w3 = w0 + 180;
    const float* w4 = w0 + 240;
    float a0 = 0.f, a1 = 0.f, a2 = 0.f, a3 = 0.f, a4 = 0.f;
#pragma unroll
    for (int c = 0; c < 60; ++c) {
      float xv = xr[c];
      a0 += w0[c] * xv; a1 += w1[c] * xv; a2 += w2[c] * xv;
      a3 += w3[c] * xv; a4 += w4[c] * xv;
    }
    ob[(size_t)(r0    ) * 57600] = f2b(a0);
    ob[(size_t)(r0 + 1) * 57600] = f2b(a1);
    ob[(size_t)(r0 + 2) * 57600] = f2b(a2);
    ob[(size_t)(r0 + 3) * 57600] = f2b(a3);
    ob[(size_t)(r0 + 4) * 57600] = f2b(a4);
  }
}

// ---------------- norm pass 1: per-site partial sums of squares ----------------
// grid (S/256, 25): chunk fc covers f in [fc*60, fc*60+60). 4 accumulators break the FMA chain.
__global__ __launch_bounds__(256) void norm_sums(const u16* __restrict__ inb,
    float* __restrict__ partials, int S) {
  int s = blockIdx.x * 256 + threadIdx.x;
  int fc = blockIdx.y;
  const u16* p = inb + (size_t)(fc * 60) * S + s;
  float a0 = 0.f, a1 = 0.f, a2 = 0.f, a3 = 0.f;
#pragma unroll
  for (int f = 0; f < 60; f += 4) {
    float v0 = b2f(p[(size_t)(f + 0) * S]); a0 += v0 * v0;
    float v1 = b2f(p[(size_t)(f + 1) * S]); a1 += v1 * v1;
    float v2 = b2f(p[(size_t)(f + 2) * S]); a2 += v2 * v2;
    float v3 = b2f(p[(size_t)(f + 3) * S]); a3 += v3 * v3;
  }
  partials[(size_t)fc * S + s] = (a0 + a1) + (a2 + a3);
}

// ---------------- norm pass 2: 64x64 tile transpose + rinv scale ----------------
// grid (S/64, 24): fully parallel over (site-tile, f-tile).
__global__ __launch_bounds__(256) void transpose_scale(const u16* __restrict__ inb,
    const float* __restrict__ partials, u16* __restrict__ outb, int S) {
  __shared__ float Ts[64 * 65];
  __shared__ float rinv[64];
  int s0 = blockIdx.x * 64, f0 = blockIdx.y * 64;
  int t = threadIdx.x; int sl = t & 63; int g = t >> 6;
  if (t < 64) {
    float tot = 0.f;
    for (int c = 0; c < 25; ++c) tot += partials[(size_t)c * S + s0 + t];
    rinv[t] = 1.f / fmaxf(sqrtf(tot), 1e-12f);
  }
  for (int e = t; e < 4096; e += 256) {
    int fr = e >> 6, sc = e & 63; int f = f0 + fr;
    Ts[fr * 65 + sc] = (f < 1500) ? b2f(inb[(size_t)f * S + s0 + sc]) : 0.f;
  }
  __syncthreads();
  for (int sr = g; sr < 64; sr += 4) {
    float v = Ts[sl * 65 + sr] * rinv[sr];
    outb[(size_t)(s0 + sr) * 1536 + f0 + sl] = f2b(v);
  }
}

// ---------------- bf16 MFMA GEMM: C[M,N] = A[M,K] * BT[N,K]^T (per batch) ----------------
// EPI 0: fp32 row-major. EPI 2: bf16 col-major (col*M+row), col<1500 only.
template<int M, int N, int K, int EPI>
__global__ __launch_bounds__(256) void gemm_bt(const u16* __restrict__ A,
    const u16* __restrict__ BT, void* __restrict__ C) {
  __shared__ __align__(16) u16 As[128 * 40];
  __shared__ __align__(16) u16 Bs[128 * 40];
  const int tid = threadIdx.x;
  const int bm = blockIdx.x, bn = blockIdx.y;
  const int lane = tid & 63;
  const int wv = tid >> 6;
  const int wm = (wv >> 1) * 64, wn = (wv & 1) * 64;
  const int lm = lane & 15, lq = lane >> 4;
  f32x4 z = {0.f, 0.f, 0.f, 0.f};
  f32x4 acc[4][4];
#pragma unroll
  for (int i = 0; i < 4; ++i)
#pragma unroll
    for (int j = 0; j < 4; ++j) acc[i][j] = z;

  for (int k0 = 0; k0 < K; k0 += 32) {
    __syncthreads();
#pragma unroll
    for (int r = 0; r < 4; ++r) {
      int idx = tid + (r << 8);              // 0..1023
      int row = (idx >> 2) & 127;
      int seg = idx & 3;
      if (r < 2) {
        const uint4* src = (const uint4*)(A + (size_t)(bm * 128 + row) * K + k0 + seg * 8);
        *(uint4*)&As[row * 40 + seg * 8] = *src;
      } else {
        const uint4* src = (const uint4*)(BT + (size_t)(bn * 128 + row) * K + k0 + seg * 8);
        *(uint4*)&Bs[row * 40 + seg * 8] = *src;
      }
    }
    __syncthreads();
    s16x8 af[4], bf[4];
#pragma unroll
    for (int i = 0; i < 4; ++i)
      af[i] = *(const s16x8*)&As[(wm + i * 16 + lm) * 40 + lq * 8];
#pragma unroll
    for (int j = 0; j < 4; ++j)
      bf[j] = *(const s16x8*)&Bs[(wn + j * 16 + lm) * 40 + lq * 8];
#pragma unroll
    for (int i = 0; i < 4; ++i)
#pragma unroll
      for (int j = 0; j < 4; ++j)
        acc[i][j] = __builtin_amdgcn_mfma_f32_16x16x32_bf16(af[i], bf[j], acc[i][j], 0, 0, 0);
  }

#pragma unroll
  for (int i = 0; i < 4; ++i) {
    int row0 = bm * 128 + wm + i * 16 + lq * 4;
#pragma unroll
    for (int j = 0; j < 4; ++j) {
      int col = bn * 128 + wn + j * 16 + lm;
      if (EPI == 0) {
        float* Cb = (float*)C;
#pragma unroll
        for (int r = 0; r < 4; ++r)
          Cb[(size_t)(row0 + r) * N + col] = acc[i][j][r];
      } else {
        if (col < 1500) {
          u16* Cb = (u16*)C;
          uint2 pk;
          pk.x = (unsigned int)f2b(acc[i][j][0]) | ((unsigned int)f2b(acc[i][j][1]) << 16);
          pk.y = (unsigned int)f2b(acc[i][j][2]) | ((unsigned int)f2b(acc[i][j][3]) << 16);
          *(uint2*)&Cb[(size_t)col * M + row0] = pk;
        }
      }
    }
  }
}

// ---------------- row softmax (2304 cols) fp32 -> bf16 ----------------
__global__ __launch_bounds__(256) void softmax_rows(const float* __restrict__ L,
                                                    u16* __restrict__ att) {
  size_t row = blockIdx.x;
  const float* Lr = L + row * 2304;
  u16* ar = att + row * 2304;
  int t = threadIdx.x;
  float v[9]; float mx = -1e30f;
#pragma unroll
  for (int i = 0; i < 9; ++i) { v[i] = Lr[t + i * 256]; mx = fmaxf(mx, v[i]); }
  __shared__ float red[256];
  red[t] = mx; __syncthreads();
  for (int st = 128; st > 0; st >>= 1) { if (t < st) red[t] = fmaxf(red[t], red[t + st]); __syncthreads(); }
  mx = red[0]; __syncthreads();
  float s = 0.f;
#pragma unroll
  for (int i = 0; i < 9; ++i) { v[i] = __expf(v[i] - mx); s += v[i]; }
  red[t] = s; __syncthreads();
  for (int st = 128; st > 0; st >>= 1) { if (t < st) red[t] += red[t + st]; __syncthreads(); }
  float rs = 1.f / red[0];
#pragma unroll
  for (int i = 0; i < 9; ++i) ar[t + i * 256] = f2b(v[i] * rs);
}

// ---------------- angular attention: parallel contraction over G2 ----------------
// dots layout (675 floats): [0..624] dots[ri*25+ci], [625..649] qn, [650..674] kn
__global__ __launch_bounds__(256) void ang_dots(const float* __restrict__ G,
    const float* __restrict__ Ma_g, const float* __restrict__ Mq_g,
    const float* __restrict__ Mk_g, float* __restrict__ dots) {
  int p = blockIdx.x;                 // 0..674, block-uniform branch
  const float* m; int ri, ci;
  if (p < 625)      { m = Ma_g; ri = p / 25; ci = p % 25; }
  else if (p < 650) { m = Mq_g; ri = p - 625; ci = ri; }
  else              { m = Mk_g; ri = p - 650; ci = ri; }
  int t = threadIdx.x;
  float a = 0.f;
  for (int e = t; e < 3600; e += 256) {
    int c = e / 60, cp = e - c * 60;
    a += m[e] * G[(size_t)(c * 25 + ri) * 1536 + cp * 25 + ci];
  }
  __shared__ float red[256];
  red[t] = a; __syncthreads();
  for (int st = 128; st > 0; st >>= 1) { if (t < st) red[t] += red[t + st]; __syncthreads(); }
  if (t == 0) dots[p] = red[0];
}

__global__ __launch_bounds__(64) void ang_finish(const float* __restrict__ dots,
                                                 float* __restrict__ Aatt) {
  int t = threadIdx.x;
  if (t < 25) {
    float rq = 1.f / fmaxf(sqrtf(dots[625 + t]), 1e-12f);
    float l[25], mx = -1e30f;
    for (int j = 0; j < 25; ++j) {
      float rk = 1.f / fmaxf(sqrtf(dots[650 + j]), 1e-12f);
      l[j] = dots[t * 25 + j] * rq * rk;
      mx = fmaxf(mx, l[j]);
    }
    float s = 0.f;
    for (int j = 0; j < 25; ++j) { l[j] = __expf(l[j] - mx); s += l[j]; }
    float rs = 1.f / s;
    for (int j = 0; j < 25; ++j) Aatt[t * 25 + j] = l[j] * rs;
  }
}

// ---------------- frequency attention: parallel Gs, then small finish ----------------
__global__ __launch_bounds__(256) void fre_gs(const float* __restrict__ G,
                                              float* __restrict__ Gs) {
  int e = blockIdx.x * 256 + threadIdx.x;   // 0..3599
  if (e >= 3600) return;
  int c = e / 60, cp = e - c * 60;
  const float* base = G + (size_t)(c * 25) * 1536 + cp * 25;
  float a = 0.f;
#pragma unroll
  for (int n = 0; n < 25; ++n) a += base[(size_t)n * 1537];
  Gs[e] = a;
}

__global__ __launch_bounds__(256) void fre_finish(const float* __restrict__ Gs_g,
    const float* __restrict__ Wfre, float* __restrict__ Fatt) {
  __shared__ float Gs[3600], T1q[3600], T1k[3600];
  __shared__ float qn[60], kn[60];
  int t = threadIdx.x;
  for (int e = t; e < 3600; e += 256) Gs[e] = Gs_g[e];
  __syncthreads();
  for (int e = t; e < 3600; e += 256) {       // T1q = Wfq*Gs, T1k = Wfk*Gs
    int u = e / 60, cp = e % 60;
    const float* wq = Wfre + u * 60;
    const float* wk = Wfre + 3600 + u * 60;
    float aq = 0.f, ak = 0.f;
    for (int c = 0; c < 60; ++c) { float g = Gs[c * 60 + cp]; aq += wq[c] * g; ak += wk[c] * g; }
    T1q[e] = aq; T1k[e] = ak;
  }
  __syncthreads();
  for (int e = t; e < 3600; e += 256) {       // dots (reuse Gs)
    int u = e / 60, v = e % 60;
    const float* wk = Wfre + 3600 + v * 60;
    float a = 0.f;
    for (int cp = 0; cp < 60; ++cp) a += T1q[u * 60 + cp] * wk[cp];
    Gs[e] = a;
  }
  for (int u = t; u < 60; u += 256) {
    const float* wq = Wfre + u * 60;
    const float* wk = Wfre + 3600 + u * 60;
    float aq = 0.f, ak = 0.f;
    for (int cp = 0; cp < 60; ++cp) { aq += T1q[u * 60 + cp] * wq[cp]; ak += T1k[u * 60 + cp] * wk[cp]; }
    qn[u] = aq; kn[u] = ak;
  }
  __syncthreads();
  if (t < 60) {
    float rq = 1.f / fmaxf(sqrtf(qn[t]), 1e-12f);
    float l[60], mx = -1e30f;
    for (int v = 0; v < 60; ++v) {
      float rk = 1.f / fmaxf(sqrtf(kn[v]), 1e-12f);
      l[v] = Gs[t * 60 + v] * rq * rk;
      mx = fmaxf(mx, l[v]);
    }
    float s = 0.f;
    for (int v = 0; v < 60; ++v) { l[v] = __expf(l[v] - mx); s += l[v]; }
    float rs = 1.f / s;
    for (int v = 0; v < 60; ++v) Fatt[t * 60 + v] = l[v] * rs;
  }
}

// ---------------- a_fea / f_fea -> CAT (bf16, per batch) ----------------
__global__ __launch_bounds__(256) void a_fea(const u16* __restrict__ PF,
    const float* __restrict__ Aatt, u16* __restrict__ CAT) {
  int hw = blockIdx.x * 256 + threadIdx.x;
  int dd = blockIdx.y;
  const u16* V = PF + ((size_t)(60 + dd)) * 230400 + hw;
  float v[25];
#pragma unroll
  for (int j = 0; j < 25; ++j) v[j] = b2f(V[(size_t)j * 9216]);
  u16* ob = CAT + (size_t)(1500 + dd * 25) * 9216 + hw;
  for (int i = 0; i < 25; ++i) {
    float a = 0.f;
#pragma unroll
    for (int j = 0; j < 25; ++j) a += Aatt[i * 25 + j] * v[j];
    ob[(size_t)i * 9216] = f2b(a);
  }
}

__global__ __launch_bounds__(256) void f_fea(const u16* __restrict__ PF,
    const float* __restrict__ Fatt, u16* __restrict__ CAT) {
  int s = blockIdx.x * 256 + threadIdx.x;
  const u16* V = PF + (size_t)120 * 230400 + s;
  float v[60];
#pragma unroll
  for (int u = 0; u < 60; ++u) v[u] = b2f(V[(size_t)u * 230400]);
  u16* ob = CAT + (size_t)27648000 + s;
  for (int u = 0; u < 60; ++u) {
    float a = 0.f;
#pragma unroll
    for (int vv = 0; vv < 60; ++vv) a += Fatt[u * 60 + vv] * v[vv];
    ob[(size_t)u * 230400] = f2b(a);
  }
}

// ---------------- precompute small weight products (once) ----------------
__global__ void precompute(const float* __restrict__ W1, const float* __restrict__ W2,
    const float* __restrict__ gamma, const float* __restrict__ beta,
    const float* __restrict__ Wang,
    float* __restrict__ Avec, float* __restrict__ Btvec,
    float* __restrict__ W1T, float* __restrict__ W2T,
    float* __restrict__ Ma, float* __restrict__ Mq, float* __restrict__ Mk) {
  int t = threadIdx.x;
  for (int e = t; e < 10800; e += 256) { int q = e / 60, j = e % 60; W1T[e] = W1[j * 180 + q]; }
  for (int e = t; e < 3600;  e += 256) { int j = e / 60, k = e % 60; W2T[e] = W2[k * 60 + j]; }
  for (int e = t; e < 3600; e += 256) {
    int c = e / 60, cp = e % 60;
    const float* Waq = Wang;            // rows 0..59
    const float* Wak = Wang + 3600;     // rows 60..119
    float ma = 0.f, mq = 0.f, mk = 0.f;
    for (int d = 0; d < 60; ++d) {
      float q = Waq[d * 60 + c], qp = Waq[d * 60 + cp];
      float k = Wak[d * 60 + c], kp = Wak[d * 60 + cp];
      ma += q * kp; mq += q * qp; mk += k * kp;
    }
    Ma[e] = ma; Mq[e] = mq; Mk[e] = mk;
  }
  if (t < 60) {
    float a = 0.f, bt = 0.f;
    for (int q = 0; q < 180; ++q) { a += gamma[q] * W1[t * 180 + q]; bt += beta[q] * W1[t * 180 + q]; }
    Avec[t] = a; Btvec[t] = bt;
  }
}

// ---------------- fused LayerNorm + MLP + residual (per batch) ----------------
__global__ __launch_bounds__(256) void fuse_ln_mlp(const u16* __restrict__ CAT,
    const float* __restrict__ xb, const float* __restrict__ gamma,
    const float* __restrict__ W1T, const float* __restrict__ W2T,
    const float* __restrict__ Avec, const float* __restrict__ Btvec,
    float* __restrict__ outb) {
  int s = blockIdx.x * 256 + threadIdx.x;
  const u16* cb = CAT + s;
  float S1[60];
#pragma unroll
  for (int j = 0; j < 60; ++j) S1[j] = 0.f;
  float sum = 0.f, sq = 0.f;
  for (int q = 0; q < 180; ++q) {
    float val = b2f(cb[(size_t)q * 230400]);
    sum += val; sq += val * val;
    float u = val * gamma[q];
    const float* w = W1T + q * 60;
#pragma unroll
    for (int j = 0; j < 60; ++j) S1[j] += u * w[j];
  }
  float mu = sum * (1.f / 180.f);
  float var = sq * (1.f / 180.f) - mu * mu;
  float inv = rsqrtf(var + 1e-5f);
  float y2[60];
#pragma unroll
  for (int k = 0; k < 60; ++k) y2[k] = 0.f;
  for (int j = 0; j < 60; ++j) {
    float y1 = inv * (S1[j] - mu * Avec[j]) + Btvec[j];
    y1 = fmaxf(y1, 0.f);
    const float* w = W2T + j * 60;
#pragma unroll
    for (int k = 0; k < 60; ++k) y2[k] += y1 * w[k];
  }
  const float* xs = xb + s;
  float* ob = outb + s;
#pragma unroll
  for (int k = 0; k < 60; ++k) ob[(size_t)k * 230400] = y2[k] + xs[(size_t)k * 230400];
}

// ---------------- launch ----------------
extern "C" void kernel_launch(void* const* d_in, const int* in_sizes, int n_in,
                              void* d_out, int out_size, void* d_ws, size_t ws_size,
                              hipStream_t stream) {
  const float* x        = (const float*)d_in[0];
  const float* w_spa_q  = (const float*)d_in[1];
  const float* w_spa_kv = (const float*)d_in[2];
  const float* w_ang    = (const float*)d_in[3];
  const float* w_fre    = (const float*)d_in[4];
  const float* ln_gamma = (const float*)d_in[5];
  const float* ln_beta  = (const float*)d_in[6];
  const float* w_mlp1   = (const float*)d_in[7];
  const float* w_mlp2   = (const float*)d_in[8];
  float* out = (float*)d_out;
  (void)in_sizes; (void)n_in; (void)out_size;

  // -------- workspace plan: three overlapping regions, peak ~224.6 MB --------
  char* ws = (char*)d_ws;
  const size_t A1 = 0;                       // U1: PF_b | PS_b
  const size_t A1_PS = 82944256;             // PF_b = 82,944,000 B
  const size_t A2 = 96934656;                // U2: G2_b -> sqn_b+skn_b -> att_b (42,467,328 B)
  const size_t A3 = 139401984;               // U3: Xb_b -> norm partials -> L_b fp32 -> CAT_b bf16
  size_t off = 224336640;                    // smalls
  auto alloc = [&](size_t bytes) -> void* {
    void* p = ws + off; off = (off + bytes + 255) & ~(size_t)255; return p;
  };
  float* Aatt  = (float*)alloc(4 * 625 * 4);    // 4 batches x 625 floats
  float* Fatt  = (float*)alloc(4 * 3600 * 4);   // 4 batches x 3600 floats
  float* Adots = (float*)alloc(4 * 675 * 4);    // 4 batches x 675 floats (dots|qn|kn)
  float* Gsg   = (float*)alloc(4 * 3600 * 4);   // 4 batches x 3600 floats (fre Gram-sum)
  float* Avec  = (float*)alloc(240);
  float* Btvec = (float*)alloc(240);
  float* W1T   = (float*)alloc(43200);
  float* W2T   = (float*)alloc(14400);
  float* Ma    = (float*)alloc(14400);
  float* Mq    = (float*)alloc(14400);
  float* Mk    = (float*)alloc(14400);

  if (off > ws_size) {  // graceful fallback: out = x (diagnosable, no fault)
    fallback_copy<<<4096, 256, 0, stream>>>(x, out, (size_t)55296000);
    return;
  }

  u16*   PF  = (u16*)(ws + A1);
  u16*   PS  = (u16*)(ws + A1_PS);
  float* G2  = (float*)(ws + A2);            //  9,437,184 B
  u16*   sqn = (u16*)(ws + A2);              // 28,311,552 B
  u16*   skn = (u16*)(ws + A2 + 28311552);   //  7,077,888 B
  u16*   att = (u16*)(ws + A2);              // 42,467,328 B
  u16*   Xb  = (u16*)(ws + A3);              // 28,311,552 B
  float* L   = (float*)(ws + A3);            // 84,934,656 B
  u16*   CAT = (u16*)(ws + A3);              // 82,944,000 B
  // norm partials live in the (dead) Xb space: consumed before L is written.
  float* Pbig   = (float*)(ws + A3);             // 25*9216*4  =   921,600 B
  float* Psmall = (float*)(ws + A3 + 921600);    // 25*2304*4  =   230,400 B

  precompute<<<1, 256, 0, stream>>>(w_mlp1, w_mlp2, ln_gamma, ln_beta, w_ang,
                                    Avec, Btvec, W1T, W2T, Ma, Mq, Mk);

  for (int b = 0; b < 4; ++b) {
    const float* xb = x + (size_t)b * 13824000;
    float* outb = out + (size_t)b * 13824000;

    // --- gram-based angular + frequency attention ---
    cast_x<<<13824, 256, 0, stream>>>(xb, Xb);
    gemm_bt<1536, 1536, 9216, 0><<<dim3(12, 12), 256, 0, stream>>>(Xb, Xb, G2);
    ang_dots<<<675, 256, 0, stream>>>(G2, Ma, Mq, Mk, Adots + b * 675);
    ang_finish<<<1, 64, 0, stream>>>(Adots + b * 675, Aatt + b * 625);
    fre_gs<<<15, 256, 0, stream>>>(G2, Gsg + b * 3600);
    fre_finish<<<1, 256, 0, stream>>>(Gsg + b * 3600, w_fre, Fatt + b * 3600);

    // --- projections ---
    proj_full<<<dim3(900, 3), 256, 0, stream>>>(xb, w_spa_q, w_ang, w_fre, PF);
    proj_sub<<<dim3(225, 4), 256, 0, stream>>>(xb, w_spa_kv, PS);

    // --- spatial attention normalize+transpose (grid-parallel 2-pass) ---
    norm_sums<<<dim3(36, 25), 256, 0, stream>>>(PF, Pbig, 9216);
    transpose_scale<<<dim3(144, 24), 256, 0, stream>>>(PF, Pbig, sqn, 9216);
    norm_sums<<<dim3(9, 25), 256, 0, stream>>>(PS, Psmall, 2304);
    transpose_scale<<<dim3(36, 24), 256, 0, stream>>>(PS, Psmall, skn, 2304);

    // --- spatial attention (sqn/skn overwrite G2; Xb+partials dead) ---
    gemm_bt<9216, 2304, 1536, 0><<<dim3(72, 18), 256, 0, stream>>>(sqn, skn, L);
    softmax_rows<<<9216, 256, 0, stream>>>(L, att);   // att overwrites sqn/skn (dead)
    gemm_bt<9216, 1536, 2304, 2><<<dim3(72, 12), 256, 0, stream>>>(att, PS + 3456000, CAT);

    // --- small attention features ---
    a_fea<<<dim3(36, 60), 256, 0, stream>>>(PF, Aatt + b * 625, CAT);
    f_fea<<<900, 256, 0, stream>>>(PF, Fatt + b * 3600, CAT);

    // --- LN + MLP + residual ---
    fuse_ln_mlp<<<900, 256, 0, stream>>>(CAT, xb, ln_gamma, W1T, W2T, Avec, Btvec, outb);
  }
}

// Round 4
// 3724.541 us; speedup vs baseline: 2.3312x; 1.1346x over previous
//
#include <hip/hip_runtime.h>
#include <hip/hip_bf16.h>

typedef unsigned short u16;
typedef float f32x4 __attribute__((ext_vector_type(4)));
typedef short s16x8 __attribute__((ext_vector_type(8)));

// B=4, C=D=60, N=25, H=W=96; HW=9216, S=230400, HW2=2304, S2=57600, DN=1500 (pad 1536)
// Phase 0 (all batches): cast -> Gram (split-K2, z-batched) -> reduce -> ang/fre attn scalars.
// Then batch-serial pipeline for the large spatial path.
// PF_b rows (180): 0..59 spa_q | 60..119 ang_v | 120..179 fre_v
// CAT_b (bf16): slot = qc*25+n (qc 0..179), inner hw.

__device__ __forceinline__ float b2f(u16 u) {
  union { unsigned int i; float f; } v; v.i = ((unsigned int)u) << 16; return v.f;
}
__device__ __forceinline__ u16 f2b(float f) {
  union { float f; unsigned int i; } v; v.f = f;
  unsigned int i = v.i + 0x7FFFu + ((v.i >> 16) & 1u);  // RNE
  return (u16)(i >> 16);
}

// ---------------- fallback (ws too small): out = x ----------------
__global__ void fallback_copy(const float* __restrict__ x, float* __restrict__ out, size_t n) {
  size_t i = (size_t)blockIdx.x * 256 + threadIdx.x;
  size_t st = (size_t)gridDim.x * 256;
  for (; i < n; i += st) out[i] = x[i];
}

// ---------------- cast x_b -> bf16 (1536,9216), pad rows zeroed ----------------
__global__ __launch_bounds__(256) void cast_x(const float* __restrict__ xb, u16* __restrict__ Xb) {
  size_t e = ((size_t)blockIdx.x * 256 + threadIdx.x) * 4;   // < 14155776
  ushort4 o;
  if (e < 13824000) {
    float4 v = *(const float4*)(xb + e);
    o.x = f2b(v.x); o.y = f2b(v.y); o.z = f2b(v.z); o.w = f2b(v.w);
  } else { o.x = 0; o.y = 0; o.z = 0; o.w = 0; }
  *(ushort4*)(Xb + e) = o;
}

// ---------------- Gram GEMM, z-batched + split-K2 ----------------
// grid (12,12,8): z = b*2+kk. Partial[z] = Xb_b[:,kk*4608:+4608] * Xb_b^T tile.
__global__ __launch_bounds__(256) void gram_gemm(const u16* __restrict__ Xall,
                                                 float* __restrict__ Pg) {
  __shared__ __align__(16) u16 As[128 * 40];
  __shared__ __align__(16) u16 Bs[128 * 40];
  const int z = blockIdx.z;
  const int b = z >> 1, kk = z & 1;
  const u16* A = Xall + (size_t)b * 14155776;      // 1536*9216
  float* C = Pg + (size_t)z * 2359296;             // 1536*1536
  const int tid = threadIdx.x;
  const int bm = blockIdx.x, bn = blockIdx.y;
  const int lane = tid & 63;
  const int wv = tid >> 6;
  const int wm = (wv >> 1) * 64, wn = (wv & 1) * 64;
  const int lm = lane & 15, lq = lane >> 4;
  f32x4 z4 = {0.f, 0.f, 0.f, 0.f};
  f32x4 acc[4][4];
#pragma unroll
  for (int i = 0; i < 4; ++i)
#pragma unroll
    for (int j = 0; j < 4; ++j) acc[i][j] = z4;

  const int kbeg = kk * 4608, kend = kbeg + 4608;
  for (int k0 = kbeg; k0 < kend; k0 += 32) {
    __syncthreads();
#pragma unroll
    for (int r = 0; r < 4; ++r) {
      int idx = tid + (r << 8);
      int row = (idx >> 2) & 127;
      int seg = idx & 3;
      if (r < 2) {
        const uint4* src = (const uint4*)(A + (size_t)(bm * 128 + row) * 9216 + k0 + seg * 8);
        *(uint4*)&As[row * 40 + seg * 8] = *src;
      } else {
        const uint4* src = (const uint4*)(A + (size_t)(bn * 128 + row) * 9216 + k0 + seg * 8);
        *(uint4*)&Bs[row * 40 + seg * 8] = *src;
      }
    }
    __syncthreads();
    s16x8 af[4], bf[4];
#pragma unroll
    for (int i = 0; i < 4; ++i)
      af[i] = *(const s16x8*)&As[(wm + i * 16 + lm) * 40 + lq * 8];
#pragma unroll
    for (int j = 0; j < 4; ++j)
      bf[j] = *(const s16x8*)&Bs[(wn + j * 16 + lm) * 40 + lq * 8];
#pragma unroll
    for (int i = 0; i < 4; ++i)
#pragma unroll
      for (int j = 0; j < 4; ++j)
        acc[i][j] = __builtin_amdgcn_mfma_f32_16x16x32_bf16(af[i], bf[j], acc[i][j], 0, 0, 0);
  }

#pragma unroll
  for (int i = 0; i < 4; ++i) {
    int row0 = bm * 128 + wm + i * 16 + lq * 4;
#pragma unroll
    for (int j = 0; j < 4; ++j) {
      int col = bn * 128 + wn + j * 16 + lm;
#pragma unroll
      for (int r = 0; r < 4; ++r)
        C[(size_t)(row0 + r) * 1536 + col] = acc[i][j][r];
    }
  }
}

// G2all[b] = Pg[2b] + Pg[2b+1]; grid (2304, 4), float4.
__global__ __launch_bounds__(256) void reduce_g2(const float* __restrict__ Pg,
                                                 float* __restrict__ G2all) {
  int b = blockIdx.y;
  size_t r = ((size_t)blockIdx.x * 256 + threadIdx.x) * 4;   // < 2359296
  float4 a = *(const float4*)(Pg + (size_t)(2 * b) * 2359296 + r);
  float4 c = *(const float4*)(Pg + (size_t)(2 * b + 1) * 2359296 + r);
  float4 o; o.x = a.x + c.x; o.y = a.y + c.y; o.z = a.z + c.z; o.w = a.w + c.w;
  *(float4*)(G2all + (size_t)b * 2359296 + r) = o;
}

// ---------------- projections (per batch) ----------------
// grid (900, 3): grp 0 -> spa_q rows (Wq), grp 1 -> ang_v (Wang+120*60), grp 2 -> fre_v (Wfre+120*60)
__global__ __launch_bounds__(256) void proj_full(const float* __restrict__ xb,
    const float* __restrict__ Wq, const float* __restrict__ Wang,
    const float* __restrict__ Wfre, u16* __restrict__ PF) {
  int s = blockIdx.x * 256 + threadIdx.x;      // 0..230399
  int grp = blockIdx.y;                        // 0..2
  const float* W = (grp == 0) ? Wq : ((grp == 1) ? (Wang + 7200) : (Wfre + 7200));
  const float* xs = xb + s;
  float xr[60];
#pragma unroll
  for (int c = 0; c < 60; ++c) xr[c] = xs[(size_t)c * 230400];
  u16* ob = PF + (size_t)grp * 13824000 + s;
  for (int r0 = 0; r0 < 60; r0 += 4) {
    const float* w0 = W + r0 * 60;
    const float* w1 = w0 + 60;
    const float* w2 = w0 + 120;
    const float* w3 = w0 + 180;
    float a0 = 0.f, a1 = 0.f, a2 = 0.f, a3 = 0.f;
#pragma unroll
    for (int c = 0; c < 60; ++c) {
      float xv = xr[c];
      a0 += w0[c] * xv; a1 += w1[c] * xv; a2 += w2[c] * xv; a3 += w3[c] * xv;
    }
    ob[(size_t)(r0    ) * 230400] = f2b(a0);
    ob[(size_t)(r0 + 1) * 230400] = f2b(a1);
    ob[(size_t)(r0 + 2) * 230400] = f2b(a2);
    ob[(size_t)(r0 + 3) * 230400] = f2b(a3);
  }
}

// grid (225, 4): each grp handles 30 of the 120 kv rows; 5-row ILP groups.
__global__ __launch_bounds__(256) void proj_sub(const float* __restrict__ xb,
    const float* __restrict__ Wkv, u16* __restrict__ PS) {
  int s2 = blockIdx.x * 256 + threadIdx.x;     // 0..57599
  int grp = blockIdx.y;                        // 0..3
  int nn = s2 / 2304; int rem = s2 - nn * 2304;
  int hy = rem / 48;  int hx = rem - hy * 48;
  const float* xs = xb + (size_t)nn * 9216 + hy * 192 + hx * 2;
  float xr[60];
#pragma unroll
  for (int c = 0; c < 60; ++c) xr[c] = xs[(size_t)c * 230400];
  u16* ob = PS + (size_t)grp * 1728000 + s2;   // 30*57600
  const float* Wg = Wkv + grp * 1800;          // 30*60
  for (int r0 = 0; r0 < 30; r0 += 5) {
    const float* w0 = Wg + r0 * 60;
    const float* w1 = w0 + 60;
    const float* w2 = w0 + 120;
    const float* w3 = w0 + 180;
    const float* w4 = w0 + 240;
    float a0 = 0.f, a1 = 0.f, a2 = 0.f, a3 = 0.f, a4 = 0.f;
#pragma unroll
    for (int c = 0; c < 60; ++c) {
      float xv = xr[c];
      a0 += w0[c] * xv; a1 += w1[c] * xv; a2 += w2[c] * xv;
      a3 += w3[c] * xv; a4 += w4[c] * xv;
    }
    ob[(size_t)(r0    ) * 57600] = f2b(a0);
    ob[(size_t)(r0 + 1) * 57600] = f2b(a1);
    ob[(size_t)(r0 + 2) * 57600] = f2b(a2);
    ob[(size_t)(r0 + 3) * 57600] = f2b(a3);
    ob[(size_t)(r0 + 4) * 57600] = f2b(a4);
  }
}

// ---------------- norm pass 1: per-site partial sums of squares ----------------
__global__ __launch_bounds__(256) void norm_sums(const u16* __restrict__ inb,
    float* __restrict__ partials, int S) {
  int s = blockIdx.x * 256 + threadIdx.x;
  int fc = blockIdx.y;
  const u16* p = inb + (size_t)(fc * 60) * S + s;
  float a0 = 0.f, a1 = 0.f, a2 = 0.f, a3 = 0.f;
#pragma unroll
  for (int f = 0; f < 60; f += 4) {
    float v0 = b2f(p[(size_t)(f + 0) * S]); a0 += v0 * v0;
    float v1 = b2f(p[(size_t)(f + 1) * S]); a1 += v1 * v1;
    float v2 = b2f(p[(size_t)(f + 2) * S]); a2 += v2 * v2;
    float v3 = b2f(p[(size_t)(f + 3) * S]); a3 += v3 * v3;
  }
  partials[(size_t)fc * S + s] = (a0 + a1) + (a2 + a3);
}

// ---------------- norm pass 2: 64x64 tile transpose + rinv scale ----------------
__global__ __launch_bounds__(256) void transpose_scale(const u16* __restrict__ inb,
    const float* __restrict__ partials, u16* __restrict__ outb, int S) {
  __shared__ float Ts[64 * 65];
  __shared__ float rinv[64];
  int s0 = blockIdx.x * 64, f0 = blockIdx.y * 64;
  int t = threadIdx.x; int sl = t & 63; int g = t >> 6;
  if (t < 64) {
    float tot = 0.f;
    for (int c = 0; c < 25; ++c) tot += partials[(size_t)c * S + s0 + t];
    rinv[t] = 1.f / fmaxf(sqrtf(tot), 1e-12f);
  }
  for (int e = t; e < 4096; e += 256) {
    int fr = e >> 6, sc = e & 63; int f = f0 + fr;
    Ts[fr * 65 + sc] = (f < 1500) ? b2f(inb[(size_t)f * S + s0 + sc]) : 0.f;
  }
  __syncthreads();
  for (int sr = g; sr < 64; sr += 4) {
    float v = Ts[sl * 65 + sr] * rinv[sr];
    outb[(size_t)(s0 + sr) * 1536 + f0 + sl] = f2b(v);
  }
}

// ---------------- bf16 MFMA GEMM: C[M,N] = A[M,K] * BT[N,K]^T (per batch) ----------------
// EPI 0: fp32 row-major. EPI 2: bf16 col-major (col*M+row), col<1500 only.
template<int M, int N, int K, int EPI>
__global__ __launch_bounds__(256) void gemm_bt(const u16* __restrict__ A,
    const u16* __restrict__ BT, void* __restrict__ C) {
  __shared__ __align__(16) u16 As[128 * 40];
  __shared__ __align__(16) u16 Bs[128 * 40];
  const int tid = threadIdx.x;
  const int bm = blockIdx.x, bn = blockIdx.y;
  const int lane = tid & 63;
  const int wv = tid >> 6;
  const int wm = (wv >> 1) * 64, wn = (wv & 1) * 64;
  const int lm = lane & 15, lq = lane >> 4;
  f32x4 z = {0.f, 0.f, 0.f, 0.f};
  f32x4 acc[4][4];
#pragma unroll
  for (int i = 0; i < 4; ++i)
#pragma unroll
    for (int j = 0; j < 4; ++j) acc[i][j] = z;

  for (int k0 = 0; k0 < K; k0 += 32) {
    __syncthreads();
#pragma unroll
    for (int r = 0; r < 4; ++r) {
      int idx = tid + (r << 8);              // 0..1023
      int row = (idx >> 2) & 127;
      int seg = idx & 3;
      if (r < 2) {
        const uint4* src = (const uint4*)(A + (size_t)(bm * 128 + row) * K + k0 + seg * 8);
        *(uint4*)&As[row * 40 + seg * 8] = *src;
      } else {
        const uint4* src = (const uint4*)(BT + (size_t)(bn * 128 + row) * K + k0 + seg * 8);
        *(uint4*)&Bs[row * 40 + seg * 8] = *src;
      }
    }
    __syncthreads();
    s16x8 af[4], bf[4];
#pragma unroll
    for (int i = 0; i < 4; ++i)
      af[i] = *(const s16x8*)&As[(wm + i * 16 + lm) * 40 + lq * 8];
#pragma unroll
    for (int j = 0; j < 4; ++j)
      bf[j] = *(const s16x8*)&Bs[(wn + j * 16 + lm) * 40 + lq * 8];
#pragma unroll
    for (int i = 0; i < 4; ++i)
#pragma unroll
      for (int j = 0; j < 4; ++j)
        acc[i][j] = __builtin_amdgcn_mfma_f32_16x16x32_bf16(af[i], bf[j], acc[i][j], 0, 0, 0);
  }

#pragma unroll
  for (int i = 0; i < 4; ++i) {
    int row0 = bm * 128 + wm + i * 16 + lq * 4;
#pragma unroll
    for (int j = 0; j < 4; ++j) {
      int col = bn * 128 + wn + j * 16 + lm;
      if (EPI == 0) {
        float* Cb = (float*)C;
#pragma unroll
        for (int r = 0; r < 4; ++r)
          Cb[(size_t)(row0 + r) * N + col] = acc[i][j][r];
      } else {
        if (col < 1500) {
          u16* Cb = (u16*)C;
          uint2 pk;
          pk.x = (unsigned int)f2b(acc[i][j][0]) | ((unsigned int)f2b(acc[i][j][1]) << 16);
          pk.y = (unsigned int)f2b(acc[i][j][2]) | ((unsigned int)f2b(acc[i][j][3]) << 16);
          *(uint2*)&Cb[(size_t)col * M + row0] = pk;
        }
      }
    }
  }
}

// ---------------- row softmax (2304 cols) fp32 -> bf16 ----------------
__global__ __launch_bounds__(256) void softmax_rows(const float* __restrict__ L,
                                                    u16* __restrict__ att) {
  size_t row = blockIdx.x;
  const float* Lr = L + row * 2304;
  u16* ar = att + row * 2304;
  int t = threadIdx.x;
  float v[9]; float mx = -1e30f;
#pragma unroll
  for (int i = 0; i < 9; ++i) { v[i] = Lr[t + i * 256]; mx = fmaxf(mx, v[i]); }
  __shared__ float red[256];
  red[t] = mx; __syncthreads();
  for (int st = 128; st > 0; st >>= 1) { if (t < st) red[t] = fmaxf(red[t], red[t + st]); __syncthreads(); }
  mx = red[0]; __syncthreads();
  float s = 0.f;
#pragma unroll
  for (int i = 0; i < 9; ++i) { v[i] = __expf(v[i] - mx); s += v[i]; }
  red[t] = s; __syncthreads();
  for (int st = 128; st > 0; st >>= 1) { if (t < st) red[t] += red[t + st]; __syncthreads(); }
  float rs = 1.f / red[0];
#pragma unroll
  for (int i = 0; i < 9; ++i) ar[t + i * 256] = f2b(v[i] * rs);
}

// ---------------- angular attention: parallel contraction over G2 (batched) ----------------
// dots layout (675 floats/batch): [0..624] dots[ri*25+ci], [625..649] qn, [650..674] kn
__global__ __launch_bounds__(256) void ang_dots(const float* __restrict__ G2all,
    const float* __restrict__ Ma_g, const float* __restrict__ Mq_g,
    const float* __restrict__ Mk_g, float* __restrict__ dotsAll) {
  int p = blockIdx.x;                 // 0..674
  int b = blockIdx.y;                 // 0..3
  const float* G = G2all + (size_t)b * 2359296;
  float* dots = dotsAll + b * 675;
  const float* m; int ri, ci;
  if (p < 625)      { m = Ma_g; ri = p / 25; ci = p % 25; }
  else if (p < 650) { m = Mq_g; ri = p - 625; ci = ri; }
  else              { m = Mk_g; ri = p - 650; ci = ri; }
  int t = threadIdx.x;
  float a = 0.f;
  for (int e = t; e < 3600; e += 256) {
    int c = e / 60, cp = e - c * 60;
    a += m[e] * G[(size_t)(c * 25 + ri) * 1536 + cp * 25 + ci];
  }
  __shared__ float red[256];
  red[t] = a; __syncthreads();
  for (int st = 128; st > 0; st >>= 1) { if (t < st) red[t] += red[t + st]; __syncthreads(); }
  if (t == 0) dots[p] = red[0];
}

__global__ __launch_bounds__(64) void ang_finish(const float* __restrict__ dotsAll,
                                                 float* __restrict__ AattAll) {
  int b = blockIdx.x;
  const float* dots = dotsAll + b * 675;
  float* Aatt = AattAll + b * 625;
  int t = threadIdx.x;
  if (t < 25) {
    float rq = 1.f / fmaxf(sqrtf(dots[625 + t]), 1e-12f);
    float l[25], mx = -1e30f;
    for (int j = 0; j < 25; ++j) {
      float rk = 1.f / fmaxf(sqrtf(dots[650 + j]), 1e-12f);
      l[j] = dots[t * 25 + j] * rq * rk;
      mx = fmaxf(mx, l[j]);
    }
    float s = 0.f;
    for (int j = 0; j < 25; ++j) { l[j] = __expf(l[j] - mx); s += l[j]; }
    float rs = 1.f / s;
    for (int j = 0; j < 25; ++j) Aatt[t * 25 + j] = l[j] * rs;
  }
}

// ---------------- frequency attention: parallel Gs (batched), then small finish ----------------
__global__ __launch_bounds__(256) void fre_gs(const float* __restrict__ G2all,
                                              float* __restrict__ GsAll) {
  int e = blockIdx.x * 256 + threadIdx.x;   // 0..3839
  int b = blockIdx.y;
  if (e >= 3600) return;
  const float* G = G2all + (size_t)b * 2359296;
  int c = e / 60, cp = e - c * 60;
  const float* base = G + (size_t)(c * 25) * 1536 + cp * 25;
  float a = 0.f;
#pragma unroll
  for (int n = 0; n < 25; ++n) a += base[(size_t)n * 1537];
  GsAll[b * 3600 + e] = a;
}

__global__ __launch_bounds__(256) void fre_finish(const float* __restrict__ GsAll,
    const float* __restrict__ Wfre, float* __restrict__ FattAll) {
  __shared__ float Gs[3600], T1q[3600], T1k[3600];
  __shared__ float qn[60], kn[60];
  int b = blockIdx.x;
  const float* Gs_g = GsAll + b * 3600;
  float* Fatt = FattAll + b * 3600;
  int t = threadIdx.x;
  for (int e = t; e < 3600; e += 256) Gs[e] = Gs_g[e];
  __syncthreads();
  for (int e = t; e < 3600; e += 256) {       // T1q = Wfq*Gs, T1k = Wfk*Gs
    int u = e / 60, cp = e % 60;
    const float* wq = Wfre + u * 60;
    const float* wk = Wfre + 3600 + u * 60;
    float aq = 0.f, ak = 0.f;
    for (int c = 0; c < 60; ++c) { float g = Gs[c * 60 + cp]; aq += wq[c] * g; ak += wk[c] * g; }
    T1q[e] = aq; T1k[e] = ak;
  }
  __syncthreads();
  for (int e = t; e < 3600; e += 256) {       // dots (reuse Gs)
    int u = e / 60, v = e % 60;
    const float* wk = Wfre + 3600 + v * 60;
    float a = 0.f;
    for (int cp = 0; cp < 60; ++cp) a += T1q[u * 60 + cp] * wk[cp];
    Gs[e] = a;
  }
  for (int u = t; u < 60; u += 256) {
    const float* wq = Wfre + u * 60;
    const float* wk = Wfre + 3600 + u * 60;
    float aq = 0.f, ak = 0.f;
    for (int cp = 0; cp < 60; ++cp) { aq += T1q[u * 60 + cp] * wq[cp]; ak += T1k[u * 60 + cp] * wk[cp]; }
    qn[u] = aq; kn[u] = ak;
  }
  __syncthreads();
  if (t < 60) {
    float rq = 1.f / fmaxf(sqrtf(qn[t]), 1e-12f);
    float l[60], mx = -1e30f;
    for (int v = 0; v < 60; ++v) {
      float rk = 1.f / fmaxf(sqrtf(kn[v]), 1e-12f);
      l[v] = Gs[t * 60 + v] * rq * rk;
      mx = fmaxf(mx, l[v]);
    }
    float s = 0.f;
    for (int v = 0; v < 60; ++v) { l[v] = __expf(l[v] - mx); s += l[v]; }
    float rs = 1.f / s;
    for (int v = 0; v < 60; ++v) Fatt[t * 60 + v] = l[v] * rs;
  }
}

// ---------------- a_fea / f_fea -> CAT (bf16, per batch) ----------------
__global__ __launch_bounds__(256) void a_fea(const u16* __restrict__ PF,
    const float* __restrict__ Aatt, u16* __restrict__ CAT) {
  int hw = blockIdx.x * 256 + threadIdx.x;
  int dd = blockIdx.y;
  const u16* V = PF + ((size_t)(60 + dd)) * 230400 + hw;
  float v[25];
#pragma unroll
  for (int j = 0; j < 25; ++j) v[j] = b2f(V[(size_t)j * 9216]);
  u16* ob = CAT + (size_t)(1500 + dd * 25) * 9216 + hw;
  for (int i = 0; i < 25; ++i) {
    float a = 0.f;
#pragma unroll
    for (int j = 0; j < 25; ++j) a += Aatt[i * 25 + j] * v[j];
    ob[(size_t)i * 9216] = f2b(a);
  }
}

__global__ __launch_bounds__(256) void f_fea(const u16* __restrict__ PF,
    const float* __restrict__ Fatt, u16* __restrict__ CAT) {
  int s = blockIdx.x * 256 + threadIdx.x;
  const u16* V = PF + (size_t)120 * 230400 + s;
  float v[60];
#pragma unroll
  for (int u = 0; u < 60; ++u) v[u] = b2f(V[(size_t)u * 230400]);
  u16* ob = CAT + (size_t)27648000 + s;
  for (int u = 0; u < 60; ++u) {
    float a = 0.f;
#pragma unroll
    for (int vv = 0; vv < 60; ++vv) a += Fatt[u * 60 + vv] * v[vv];
    ob[(size_t)u * 230400] = f2b(a);
  }
}

// ---------------- precompute small weight products (once) ----------------
__global__ void precompute(const float* __restrict__ W1, const float* __restrict__ W2,
    const float* __restrict__ gamma, const float* __restrict__ beta,
    const float* __restrict__ Wang,
    float* __restrict__ Avec, float* __restrict__ Btvec,
    float* __restrict__ W1T, float* __restrict__ W2T,
    float* __restrict__ Ma, float* __restrict__ Mq, float* __restrict__ Mk) {
  int t = threadIdx.x;
  for (int e = t; e < 10800; e += 256) { int q = e / 60, j = e % 60; W1T[e] = W1[j * 180 + q]; }
  for (int e = t; e < 3600;  e += 256) { int j = e / 60, k = e % 60; W2T[e] = W2[k * 60 + j]; }
  for (int e = t; e < 3600; e += 256) {
    int c = e / 60, cp = e % 60;
    const float* Waq = Wang;            // rows 0..59
    const float* Wak = Wang + 3600;     // rows 60..119
    float ma = 0.f, mq = 0.f, mk = 0.f;
    for (int d = 0; d < 60; ++d) {
      float q = Waq[d * 60 + c], qp = Waq[d * 60 + cp];
      float k = Wak[d * 60 + c], kp = Wak[d * 60 + cp];
      ma += q * kp; mq += q * qp; mk += k * kp;
    }
    Ma[e] = ma; Mq[e] = mq; Mk[e] = mk;
  }
  if (t < 60) {
    float a = 0.f, bt = 0.f;
    for (int q = 0; q < 180; ++q) { a += gamma[q] * W1[t * 180 + q]; bt += beta[q] * W1[t * 180 + q]; }
    Avec[t] = a; Btvec[t] = bt;
  }
}

// ---------------- fused LayerNorm + MLP + residual (per batch) ----------------
__global__ __launch_bounds__(256) void fuse_ln_mlp(const u16* __restrict__ CAT,
    const float* __restrict__ xb, const float* __restrict__ gamma,
    const float* __restrict__ W1T, const float* __restrict__ W2T,
    const float* __restrict__ Avec, const float* __restrict__ Btvec,
    float* __restrict__ outb) {
  int s = blockIdx.x * 256 + threadIdx.x;
  const u16* cb = CAT + s;
  float S1[60];
#pragma unroll
  for (int j = 0; j < 60; ++j) S1[j] = 0.f;
  float sum = 0.f, sq = 0.f;
  for (int q = 0; q < 180; ++q) {
    float val = b2f(cb[(size_t)q * 230400]);
    sum += val; sq += val * val;
    float u = val * gamma[q];
    const float* w = W1T + q * 60;
#pragma unroll
    for (int j = 0; j < 60; ++j) S1[j] += u * w[j];
  }
  float mu = sum * (1.f / 180.f);
  float var = sq * (1.f / 180.f) - mu * mu;
  float inv = rsqrtf(var + 1e-5f);
  float y2[60];
#pragma unroll
  for (int k = 0; k < 60; ++k) y2[k] = 0.f;
  for (int j = 0; j < 60; ++j) {
    float y1 = inv * (S1[j] - mu * Avec[j]) + Btvec[j];
    y1 = fmaxf(y1, 0.f);
    const float* w = W2T + j * 60;
#pragma unroll
    for (int k = 0; k < 60; ++k) y2[k] += y1 * w[k];
  }
  const float* xs = xb + s;
  float* ob = outb + s;
#pragma unroll
  for (int k = 0; k < 60; ++k) ob[(size_t)k * 230400] = y2[k] + xs[(size_t)k * 230400];
}

// ---------------- launch ----------------
extern "C" void kernel_launch(void* const* d_in, const int* in_sizes, int n_in,
                              void* d_out, int out_size, void* d_ws, size_t ws_size,
                              hipStream_t stream) {
  const float* x        = (const float*)d_in[0];
  const float* w_spa_q  = (const float*)d_in[1];
  const float* w_spa_kv = (const float*)d_in[2];
  const float* w_ang    = (const float*)d_in[3];
  const float* w_fre    = (const float*)d_in[4];
  const float* ln_gamma = (const float*)d_in[5];
  const float* ln_beta  = (const float*)d_in[6];
  const float* w_mlp1   = (const float*)d_in[7];
  const float* w_mlp2   = (const float*)d_in[8];
  float* out = (float*)d_out;
  (void)in_sizes; (void)n_in; (void)out_size;

  // -------- workspace plan --------
  // Phase 0: Xb_all [0, 113,246,208) | Pg [113,246,208, 188,743,680)
  //          then G2_all [0, 37,748,736) (Xb dead), consumed by ang/fre before batch loop.
  // Batch loop regions (unchanged from prior rounds):
  //   A1: PF_b | PS_b   A2: sqn+skn -> att   A3: partials -> L fp32 -> CAT bf16
  char* ws = (char*)d_ws;
  const size_t A1 = 0;
  const size_t A1_PS = 82944256;             // PF_b = 82,944,000 B
  const size_t A2 = 96934656;
  const size_t A3 = 139401984;
  size_t off = 224336640;                    // smalls
  auto alloc = [&](size_t bytes) -> void* {
    void* p = ws + off; off = (off + bytes + 255) & ~(size_t)255; return p;
  };
  float* Aatt  = (float*)alloc(4 * 625 * 4);
  float* Fatt  = (float*)alloc(4 * 3600 * 4);
  float* Adots = (float*)alloc(4 * 675 * 4);
  float* Gsg   = (float*)alloc(4 * 3600 * 4);
  float* Avec  = (float*)alloc(240);
  float* Btvec = (float*)alloc(240);
  float* W1T   = (float*)alloc(43200);
  float* W2T   = (float*)alloc(14400);
  float* Ma    = (float*)alloc(14400);
  float* Mq    = (float*)alloc(14400);
  float* Mk    = (float*)alloc(14400);

  if (off > ws_size) {  // graceful fallback: out = x (diagnosable, no fault)
    fallback_copy<<<4096, 256, 0, stream>>>(x, out, (size_t)55296000);
    return;
  }

  // phase-0 buffers
  u16*   XbAll = (u16*)(ws);                       // 4 x 28,311,552 B
  float* Pg    = (float*)(ws + 113246208);         // 8 x  9,437,184 B
  float* G2all = (float*)(ws);                     // 4 x  9,437,184 B (after Xb dead)

  // batch-loop buffers
  u16*   PF  = (u16*)(ws + A1);
  u16*   PS  = (u16*)(ws + A1_PS);
  u16*   sqn = (u16*)(ws + A2);              // 28,311,552 B
  u16*   skn = (u16*)(ws + A2 + 28311552);   //  7,077,888 B
  u16*   att = (u16*)(ws + A2);              // 42,467,328 B
  float* L   = (float*)(ws + A3);            // 84,934,656 B
  u16*   CAT = (u16*)(ws + A3);              // 82,944,000 B
  float* Pbig   = (float*)(ws + A3);             // 25*9216*4
  float* Psmall = (float*)(ws + A3 + 921600);    // 25*2304*4

  precompute<<<1, 256, 0, stream>>>(w_mlp1, w_mlp2, ln_gamma, ln_beta, w_ang,
                                    Avec, Btvec, W1T, W2T, Ma, Mq, Mk);

  // ---- phase 0: all-batch Gram + angular/frequency attention scalars ----
  for (int b = 0; b < 4; ++b)
    cast_x<<<13824, 256, 0, stream>>>(x + (size_t)b * 13824000, XbAll + (size_t)b * 14155776);
  gram_gemm<<<dim3(12, 12, 8), 256, 0, stream>>>(XbAll, Pg);
  reduce_g2<<<dim3(2304, 4), 256, 0, stream>>>(Pg, G2all);
  ang_dots<<<dim3(675, 4), 256, 0, stream>>>(G2all, Ma, Mq, Mk, Adots);
  ang_finish<<<4, 64, 0, stream>>>(Adots, Aatt);
  fre_gs<<<dim3(15, 4), 256, 0, stream>>>(G2all, Gsg);
  fre_finish<<<4, 256, 0, stream>>>(Gsg, w_fre, Fatt);

  // ---- per-batch spatial pipeline ----
  for (int b = 0; b < 4; ++b) {
    const float* xb = x + (size_t)b * 13824000;
    float* outb = out + (size_t)b * 13824000;

    // --- projections (PF overwrites G2all space; G2all already consumed) ---
    proj_full<<<dim3(900, 3), 256, 0, stream>>>(xb, w_spa_q, w_ang, w_fre, PF);
    proj_sub<<<dim3(225, 4), 256, 0, stream>>>(xb, w_spa_kv, PS);

    // --- spatial attention normalize+transpose (grid-parallel 2-pass) ---
    norm_sums<<<dim3(36, 25), 256, 0, stream>>>(PF, Pbig, 9216);
    transpose_scale<<<dim3(144, 24), 256, 0, stream>>>(PF, Pbig, sqn, 9216);
    norm_sums<<<dim3(9, 25), 256, 0, stream>>>(PS, Psmall, 2304);
    transpose_scale<<<dim3(36, 24), 256, 0, stream>>>(PS, Psmall, skn, 2304);

    // --- spatial attention ---
    gemm_bt<9216, 2304, 1536, 0><<<dim3(72, 18), 256, 0, stream>>>(sqn, skn, L);
    softmax_rows<<<9216, 256, 0, stream>>>(L, att);   // att overwrites sqn/skn (dead)
    gemm_bt<9216, 1536, 2304, 2><<<dim3(72, 12), 256, 0, stream>>>(att, PS + 3456000, CAT);

    // --- small attention features ---
    a_fea<<<dim3(36, 60), 256, 0, stream>>>(PF, Aatt + b * 625, CAT);
    f_fea<<<900, 256, 0, stream>>>(PF, Fatt + b * 3600, CAT);

    // --- LN + MLP + residual ---
    fuse_ln_mlp<<<900, 256, 0, stream>>>(CAT, xb, ln_gamma, W1T, W2T, Avec, Btvec, outb);
  }
}

// Round 5
// 3622.182 us; speedup vs baseline: 2.3971x; 1.0283x over previous
//
#include <hip/hip_runtime.h>
#include <hip/hip_bf16.h>

typedef unsigned short u16;
typedef float f32x4 __attribute__((ext_vector_type(4)));
typedef short s16x8 __attribute__((ext_vector_type(8)));

// B=4, C=D=60, N=25, H=W=96; HW=9216, S=230400, HW2=2304, S2=57600, DN=1500 (pad 1536)
// Phase 0 (all batches): cast -> Gram upper-triangle (split-K2, z-batched) -> reduce+mirror
//                        -> ang/fre attn scalars.
// Then batch-serial pipeline for the large spatial path.
// PF_b rows (180): 0..59 spa_q | 60..119 ang_v | 120..179 fre_v
// CAT_b (bf16): slot = qc*25+n (qc 0..179), inner hw.

__device__ __forceinline__ float b2f(u16 u) {
  union { unsigned int i; float f; } v; v.i = ((unsigned int)u) << 16; return v.f;
}
__device__ __forceinline__ u16 f2b(float f) {
  union { float f; unsigned int i; } v; v.f = f;
  unsigned int i = v.i + 0x7FFFu + ((v.i >> 16) & 1u);  // RNE
  return (u16)(i >> 16);
}

// ---------------- fallback (ws too small): out = x ----------------
__global__ void fallback_copy(const float* __restrict__ x, float* __restrict__ out, size_t n) {
  size_t i = (size_t)blockIdx.x * 256 + threadIdx.x;
  size_t st = (size_t)gridDim.x * 256;
  for (; i < n; i += st) out[i] = x[i];
}

// ---------------- cast x_b -> bf16 (1536,9216), pad rows zeroed ----------------
__global__ __launch_bounds__(256) void cast_x(const float* __restrict__ xb, u16* __restrict__ Xb) {
  size_t e = ((size_t)blockIdx.x * 256 + threadIdx.x) * 4;   // < 14155776
  ushort4 o;
  if (e < 13824000) {
    float4 v = *(const float4*)(xb + e);
    o.x = f2b(v.x); o.y = f2b(v.y); o.z = f2b(v.z); o.w = f2b(v.w);
  } else { o.x = 0; o.y = 0; o.z = 0; o.w = 0; }
  *(ushort4*)(Xb + e) = o;
}

// ---------------- Gram GEMM, upper-triangle tiles, z-batched + split-K2 ----------------
// grid (78,1,8): z = b*2+kk. x -> bijective XCD chunk swizzle -> triangular (bm<=bn).
// Partial[z](tile bm,bn) = Xb_b[bm rows, kk*4608:+4608] * Xb_b[bn rows, same]^T.
__global__ __launch_bounds__(256) void gram_gemm(const u16* __restrict__ Xall,
                                                 float* __restrict__ Pg) {
  __shared__ __align__(16) u16 As[128 * 40];
  __shared__ __align__(16) u16 Bs[128 * 40];
  const int z = blockIdx.z;
  const int b = z >> 1, kk = z & 1;
  const u16* A = Xall + (size_t)b * 14155776;      // 1536*9216
  float* C = Pg + (size_t)z * 2359296;             // 1536*1536
  // bijective XCD chunk swizzle (nwg=78: q=9, r=6)  [m204]
  {
  }
  int p = blockIdx.x;
  int xcd = p & 7, loc = p >> 3;
  int wg = (xcd < 6 ? xcd * 10 : 60 + (xcd - 6) * 9) + loc;
  // triangular decode: row sizes 12,11,...,1
  int bm = 0, rem = wg;
  while (rem >= 12 - bm) { rem -= 12 - bm; ++bm; }
  int bn = bm + rem;

  const int tid = threadIdx.x;
  const int lane = tid & 63;
  const int wv = tid >> 6;
  const int wm = (wv >> 1) * 64, wn = (wv & 1) * 64;
  const int lm = lane & 15, lq = lane >> 4;
  f32x4 z4 = {0.f, 0.f, 0.f, 0.f};
  f32x4 acc[4][4];
#pragma unroll
  for (int i = 0; i < 4; ++i)
#pragma unroll
    for (int j = 0; j < 4; ++j) acc[i][j] = z4;

  const int kbeg = kk * 4608, kend = kbeg + 4608;
  for (int k0 = kbeg; k0 < kend; k0 += 32) {
    __syncthreads();
#pragma unroll
    for (int r = 0; r < 4; ++r) {
      int idx = tid + (r << 8);
      int row = (idx >> 2) & 127;
      int seg = idx & 3;
      if (r < 2) {
        const uint4* src = (const uint4*)(A + (size_t)(bm * 128 + row) * 9216 + k0 + seg * 8);
        *(uint4*)&As[row * 40 + seg * 8] = *src;
      } else {
        const uint4* src = (const uint4*)(A + (size_t)(bn * 128 + row) * 9216 + k0 + seg * 8);
        *(uint4*)&Bs[row * 40 + seg * 8] = *src;
      }
    }
    __syncthreads();
    s16x8 af[4], bf[4];
#pragma unroll
    for (int i = 0; i < 4; ++i)
      af[i] = *(const s16x8*)&As[(wm + i * 16 + lm) * 40 + lq * 8];
#pragma unroll
    for (int j = 0; j < 4; ++j)
      bf[j] = *(const s16x8*)&Bs[(wn + j * 16 + lm) * 40 + lq * 8];
#pragma unroll
    for (int i = 0; i < 4; ++i)
#pragma unroll
      for (int j = 0; j < 4; ++j)
        acc[i][j] = __builtin_amdgcn_mfma_f32_16x16x32_bf16(af[i], bf[j], acc[i][j], 0, 0, 0);
  }

#pragma unroll
  for (int i = 0; i < 4; ++i) {
    int row0 = bm * 128 + wm + i * 16 + lq * 4;
#pragma unroll
    for (int j = 0; j < 4; ++j) {
      int col = bn * 128 + wn + j * 16 + lm;
#pragma unroll
      for (int r = 0; r < 4; ++r)
        C[(size_t)(row0 + r) * 1536 + col] = acc[i][j][r];
    }
  }
}

// ---------------- reduce split-K partials + mirror to lower triangle ----------------
// grid (300, 4): upper 64x64 sub-tiles (ti<=tj over 24). Direct write coalesced;
// mirrored write via LDS 64x65 transpose. Diagonal sub-tiles skip the mirror
// (their transposed values are identical — diagonal 128-tiles were computed in full).
__global__ __launch_bounds__(256) void reduce_mirror(const float* __restrict__ Pg,
                                                     float* __restrict__ G2all) {
  __shared__ float Ts[64 * 65];
  int b = blockIdx.y;
  int p = blockIdx.x;
  int ti = 0, rem = p;
  while (rem >= 24 - ti) { rem -= 24 - ti; ++ti; }
  int tj = ti + rem;
  const float* P0 = Pg + (size_t)(2 * b) * 2359296;
  const float* P1 = P0 + 2359296;
  float* G = G2all + (size_t)b * 2359296;
  int t = threadIdx.x;
  int r = t >> 4;                 // 0..15
  int c4 = (t & 15) * 4;          // 0..60
#pragma unroll
  for (int k = 0; k < 4; ++k) {
    int rr = r + 16 * k;
    size_t src = (size_t)(ti * 64 + rr) * 1536 + tj * 64 + c4;
    float4 a = *(const float4*)(P0 + src);
    float4 c = *(const float4*)(P1 + src);
    float4 s; s.x = a.x + c.x; s.y = a.y + c.y; s.z = a.z + c.z; s.w = a.w + c.w;
    *(float4*)(G + src) = s;
    Ts[rr * 65 + c4 + 0] = s.x;
    Ts[rr * 65 + c4 + 1] = s.y;
    Ts[rr * 65 + c4 + 2] = s.z;
    Ts[rr * 65 + c4 + 3] = s.w;
  }
  __syncthreads();
  if (ti != tj) {
#pragma unroll
    for (int k = 0; k < 4; ++k) {
      int rr = r + 16 * k;        // row within mirrored tile
      size_t dst = (size_t)(tj * 64 + rr) * 1536 + ti * 64 + c4;
      float4 s;
      s.x = Ts[(c4 + 0) * 65 + rr];
      s.y = Ts[(c4 + 1) * 65 + rr];
      s.z = Ts[(c4 + 2) * 65 + rr];
      s.w = Ts[(c4 + 3) * 65 + rr];
      *(float4*)(G + dst) = s;
    }
  }
}

// ---------------- projections (per batch) ----------------
// grid (900, 3): grp 0 -> spa_q rows (Wq), grp 1 -> ang_v (Wang+120*60), grp 2 -> fre_v (Wfre+120*60)
__global__ __launch_bounds__(256) void proj_full(const float* __restrict__ xb,
    const float* __restrict__ Wq, const float* __restrict__ Wang,
    const float* __restrict__ Wfre, u16* __restrict__ PF) {
  int s = blockIdx.x * 256 + threadIdx.x;      // 0..230399
  int grp = blockIdx.y;                        // 0..2
  const float* W = (grp == 0) ? Wq : ((grp == 1) ? (Wang + 7200) : (Wfre + 7200));
  const float* xs = xb + s;
  float xr[60];
#pragma unroll
  for (int c = 0; c < 60; ++c) xr[c] = xs[(size_t)c * 230400];
  u16* ob = PF + (size_t)grp * 13824000 + s;
  for (int r0 = 0; r0 < 60; r0 += 4) {
    const float* w0 = W + r0 * 60;
    const float* w1 = w0 + 60;
    const float* w2 = w0 + 120;
    const float* w3 = w0 + 180;
    float a0 = 0.f, a1 = 0.f, a2 = 0.f, a3 = 0.f;
#pragma unroll
    for (int c = 0; c < 60; ++c) {
      float xv = xr[c];
      a0 += w0[c] * xv; a1 += w1[c] * xv; a2 += w2[c] * xv; a3 += w3[c] * xv;
    }
    ob[(size_t)(r0    ) * 230400] = f2b(a0);
    ob[(size_t)(r0 + 1) * 230400] = f2b(a1);
    ob[(size_t)(r0 + 2) * 230400] = f2b(a2);
    ob[(size_t)(r0 + 3) * 230400] = f2b(a3);
  }
}

// grid (225, 4): each grp handles 30 of the 120 kv rows; 5-row ILP groups.
__global__ __launch_bounds__(256) void proj_sub(const float* __restrict__ xb,
    const float* __restrict__ Wkv, u16* __restrict__ PS) {
  int s2 = blockIdx.x * 256 + threadIdx.x;     // 0..57599
  int grp = blockIdx.y;                        // 0..3
  int nn = s2 / 2304; int rem = s2 - nn * 2304;
  int hy = rem / 48;  int hx = rem - hy * 48;
  const float* xs = xb + (size_t)nn * 9216 + hy * 192 + hx * 2;
  float xr[60];
#pragma unroll
  for (int c = 0; c < 60; ++c) xr[c] = xs[(size_t)c * 230400];
  u16* ob = PS + (size_t)grp * 1728000 + s2;   // 30*57600
  const float* Wg = Wkv + grp * 1800;          // 30*60
  for (int r0 = 0; r0 < 30; r0 += 5) {
    const float* w0 = Wg + r0 * 60;
    const float* w1 = w0 + 60;
    const float* w2 = w0 + 120;
    const float* w3 = w0 + 180;
    const float* w4 = w0 + 240;
    float a0 = 0.f, a1 = 0.f, a2 = 0.f, a3 = 0.f, a4 = 0.f;
#pragma unroll
    for (int c = 0; c < 60; ++c) {
      float xv = xr[c];
      a0 += w0[c] * xv; a1 += w1[c] * xv; a2 += w2[c] * xv;
      a3 += w3[c] * xv; a4 += w4[c] * xv;
    }
    ob[(size_t)(r0    ) * 57600] = f2b(a0);
    ob[(size_t)(r0 + 1) * 57600] = f2b(a1);
    ob[(size_t)(r0 + 2) * 57600] = f2b(a2);
    ob[(size_t)(r0 + 3) * 57600] = f2b(a3);
    ob[(size_t)(r0 + 4) * 57600] = f2b(a4);
  }
}

// ---------------- norm pass 1: per-site partial sums of squares ----------------
__global__ __launch_bounds__(256) void norm_sums(const u16* __restrict__ inb,
    float* __restrict__ partials, int S) {
  int s = blockIdx.x * 256 + threadIdx.x;
  int fc = blockIdx.y;
  const u16* p = inb + (size_t)(fc * 60) * S + s;
  float a0 = 0.f, a1 = 0.f, a2 = 0.f, a3 = 0.f;
#pragma unroll
  for (int f = 0; f < 60; f += 4) {
    float v0 = b2f(p[(size_t)(f + 0) * S]); a0 += v0 * v0;
    float v1 = b2f(p[(size_t)(f + 1) * S]); a1 += v1 * v1;
    float v2 = b2f(p[(size_t)(f + 2) * S]); a2 += v2 * v2;
    float v3 = b2f(p[(size_t)(f + 3) * S]); a3 += v3 * v3;
  }
  partials[(size_t)fc * S + s] = (a0 + a1) + (a2 + a3);
}

// ---------------- norm pass 2: 64x64 tile transpose + rinv scale ----------------
__global__ __launch_bounds__(256) void transpose_scale(const u16* __restrict__ inb,
    const float* __restrict__ partials, u16* __restrict__ outb, int S) {
  __shared__ float Ts[64 * 65];
  __shared__ float rinv[64];
  int s0 = blockIdx.x * 64, f0 = blockIdx.y * 64;
  int t = threadIdx.x; int sl = t & 63; int g = t >> 6;
  if (t < 64) {
    float tot = 0.f;
    for (int c = 0; c < 25; ++c) tot += partials[(size_t)c * S + s0 + t];
    rinv[t] = 1.f / fmaxf(sqrtf(tot), 1e-12f);
  }
  for (int e = t; e < 4096; e += 256) {
    int fr = e >> 6, sc = e & 63; int f = f0 + fr;
    Ts[fr * 65 + sc] = (f < 1500) ? b2f(inb[(size_t)f * S + s0 + sc]) : 0.f;
  }
  __syncthreads();
  for (int sr = g; sr < 64; sr += 4) {
    float v = Ts[sl * 65 + sr] * rinv[sr];
    outb[(size_t)(s0 + sr) * 1536 + f0 + sl] = f2b(v);
  }
}

// ---------------- bf16 MFMA GEMM: C[M,N] = A[M,K] * BT[N,K]^T (per batch) ----------------
// EPI 0: fp32 row-major. EPI 2: bf16 col-major (col*M+row), col<1500 only.
template<int M, int N, int K, int EPI>
__global__ __launch_bounds__(256) void gemm_bt(const u16* __restrict__ A,
    const u16* __restrict__ BT, void* __restrict__ C) {
  __shared__ __align__(16) u16 As[128 * 40];
  __shared__ __align__(16) u16 Bs[128 * 40];
  const int tid = threadIdx.x;
  const int bm = blockIdx.x, bn = blockIdx.y;
  const int lane = tid & 63;
  const int wv = tid >> 6;
  const int wm = (wv >> 1) * 64, wn = (wv & 1) * 64;
  const int lm = lane & 15, lq = lane >> 4;
  f32x4 z = {0.f, 0.f, 0.f, 0.f};
  f32x4 acc[4][4];
#pragma unroll
  for (int i = 0; i < 4; ++i)
#pragma unroll
    for (int j = 0; j < 4; ++j) acc[i][j] = z;

  for (int k0 = 0; k0 < K; k0 += 32) {
    __syncthreads();
#pragma unroll
    for (int r = 0; r < 4; ++r) {
      int idx = tid + (r << 8);              // 0..1023
      int row = (idx >> 2) & 127;
      int seg = idx & 3;
      if (r < 2) {
        const uint4* src = (const uint4*)(A + (size_t)(bm * 128 + row) * K + k0 + seg * 8);
        *(uint4*)&As[row * 40 + seg * 8] = *src;
      } else {
        const uint4* src = (const uint4*)(BT + (size_t)(bn * 128 + row) * K + k0 + seg * 8);
        *(uint4*)&Bs[row * 40 + seg * 8] = *src;
      }
    }
    __syncthreads();
    s16x8 af[4], bf[4];
#pragma unroll
    for (int i = 0; i < 4; ++i)
      af[i] = *(const s16x8*)&As[(wm + i * 16 + lm) * 40 + lq * 8];
#pragma unroll
    for (int j = 0; j < 4; ++j)
      bf[j] = *(const s16x8*)&Bs[(wn + j * 16 + lm) * 40 + lq * 8];
#pragma unroll
    for (int i = 0; i < 4; ++i)
#pragma unroll
      for (int j = 0; j < 4; ++j)
        acc[i][j] = __builtin_amdgcn_mfma_f32_16x16x32_bf16(af[i], bf[j], acc[i][j], 0, 0, 0);
  }

#pragma unroll
  for (int i = 0; i < 4; ++i) {
    int row0 = bm * 128 + wm + i * 16 + lq * 4;
#pragma unroll
    for (int j = 0; j < 4; ++j) {
      int col = bn * 128 + wn + j * 16 + lm;
      if (EPI == 0) {
        float* Cb = (float*)C;
#pragma unroll
        for (int r = 0; r < 4; ++r)
          Cb[(size_t)(row0 + r) * N + col] = acc[i][j][r];
      } else {
        if (col < 1500) {
          u16* Cb = (u16*)C;
          uint2 pk;
          pk.x = (unsigned int)f2b(acc[i][j][0]) | ((unsigned int)f2b(acc[i][j][1]) << 16);
          pk.y = (unsigned int)f2b(acc[i][j][2]) | ((unsigned int)f2b(acc[i][j][3]) << 16);
          *(uint2*)&Cb[(size_t)col * M + row0] = pk;
        }
      }
    }
  }
}

// ---------------- row softmax (2304 cols) fp32 -> bf16 ----------------
__global__ __launch_bounds__(256) void softmax_rows(const float* __restrict__ L,
                                                    u16* __restrict__ att) {
  size_t row = blockIdx.x;
  const float* Lr = L + row * 2304;
  u16* ar = att + row * 2304;
  int t = threadIdx.x;
  float v[9]; float mx = -1e30f;
#pragma unroll
  for (int i = 0; i < 9; ++i) { v[i] = Lr[t + i * 256]; mx = fmaxf(mx, v[i]); }
  __shared__ float red[256];
  red[t] = mx; __syncthreads();
  for (int st = 128; st > 0; st >>= 1) { if (t < st) red[t] = fmaxf(red[t], red[t + st]); __syncthreads(); }
  mx = red[0]; __syncthreads();
  float s = 0.f;
#pragma unroll
  for (int i = 0; i < 9; ++i) { v[i] = __expf(v[i] - mx); s += v[i]; }
  red[t] = s; __syncthreads();
  for (int st = 128; st > 0; st >>= 1) { if (t < st) red[t] += red[t + st]; __syncthreads(); }
  float rs = 1.f / red[0];
#pragma unroll
  for (int i = 0; i < 9; ++i) ar[t + i * 256] = f2b(v[i] * rs);
}

// ---------------- angular attention: parallel contraction over G2 (batched) ----------------
// dots layout (675 floats/batch): [0..624] dots[ri*25+ci], [625..649] qn, [650..674] kn
__global__ __launch_bounds__(256) void ang_dots(const float* __restrict__ G2all,
    const float* __restrict__ Ma_g, const float* __restrict__ Mq_g,
    const float* __restrict__ Mk_g, float* __restrict__ dotsAll) {
  int p = blockIdx.x;                 // 0..674
  int b = blockIdx.y;                 // 0..3
  const float* G = G2all + (size_t)b * 2359296;
  float* dots = dotsAll + b * 675;
  const float* m; int ri, ci;
  if (p < 625)      { m = Ma_g; ri = p / 25; ci = p % 25; }
  else if (p < 650) { m = Mq_g; ri = p - 625; ci = ri; }
  else              { m = Mk_g; ri = p - 650; ci = ri; }
  int t = threadIdx.x;
  float a = 0.f;
  for (int e = t; e < 3600; e += 256) {
    int c = e / 60, cp = e - c * 60;
    a += m[e] * G[(size_t)(c * 25 + ri) * 1536 + cp * 25 + ci];
  }
  __shared__ float red[256];
  red[t] = a; __syncthreads();
  for (int st = 128; st > 0; st >>= 1) { if (t < st) red[t] += red[t + st]; __syncthreads(); }
  if (t == 0) dots[p] = red[0];
}

__global__ __launch_bounds__(64) void ang_finish(const float* __restrict__ dotsAll,
                                                 float* __restrict__ AattAll) {
  int b = blockIdx.x;
  const float* dots = dotsAll + b * 675;
  float* Aatt = AattAll + b * 625;
  int t = threadIdx.x;
  if (t < 25) {
    float rq = 1.f / fmaxf(sqrtf(dots[625 + t]), 1e-12f);
    float l[25], mx = -1e30f;
    for (int j = 0; j < 25; ++j) {
      float rk = 1.f / fmaxf(sqrtf(dots[650 + j]), 1e-12f);
      l[j] = dots[t * 25 + j] * rq * rk;
      mx = fmaxf(mx, l[j]);
    }
    float s = 0.f;
    for (int j = 0; j < 25; ++j) { l[j] = __expf(l[j] - mx); s += l[j]; }
    float rs = 1.f / s;
    for (int j = 0; j < 25; ++j) Aatt[t * 25 + j] = l[j] * rs;
  }
}

// ---------------- frequency attention: parallel Gs (batched), then small finish ----------------
__global__ __launch_bounds__(256) void fre_gs(const float* __restrict__ G2all,
                                              float* __restrict__ GsAll) {
  int e = blockIdx.x * 256 + threadIdx.x;   // 0..3839
  int b = blockIdx.y;
  if (e >= 3600) return;
  const float* G = G2all + (size_t)b * 2359296;
  int c = e / 60, cp = e - c * 60;
  const float* base = G + (size_t)(c * 25) * 1536 + cp * 25;
  float a = 0.f;
#pragma unroll
  for (int n = 0; n < 25; ++n) a += base[(size_t)n * 1537];
  GsAll[b * 3600 + e] = a;
}

__global__ __launch_bounds__(256) void fre_finish(const float* __restrict__ GsAll,
    const float* __restrict__ Wfre, float* __restrict__ FattAll) {
  __shared__ float Gs[3600], T1q[3600], T1k[3600];
  __shared__ float qn[60], kn[60];
  int b = blockIdx.x;
  const float* Gs_g = GsAll + b * 3600;
  float* Fatt = FattAll + b * 3600;
  int t = threadIdx.x;
  for (int e = t; e < 3600; e += 256) Gs[e] = Gs_g[e];
  __syncthreads();
  for (int e = t; e < 3600; e += 256) {       // T1q = Wfq*Gs, T1k = Wfk*Gs
    int u = e / 60, cp = e % 60;
    const float* wq = Wfre + u * 60;
    const float* wk = Wfre + 3600 + u * 60;
    float aq = 0.f, ak = 0.f;
    for (int c = 0; c < 60; ++c) { float g = Gs[c * 60 + cp]; aq += wq[c] * g; ak += wk[c] * g; }
    T1q[e] = aq; T1k[e] = ak;
  }
  __syncthreads();
  for (int e = t; e < 3600; e += 256) {       // dots (reuse Gs)
    int u = e / 60, v = e % 60;
    const float* wk = Wfre + 3600 + v * 60;
    float a = 0.f;
    for (int cp = 0; cp < 60; ++cp) a += T1q[u * 60 + cp] * wk[cp];
    Gs[e] = a;
  }
  for (int u = t; u < 60; u += 256) {
    const float* wq = Wfre + u * 60;
    const float* wk = Wfre + 3600 + u * 60;
    float aq = 0.f, ak = 0.f;
    for (int cp = 0; cp < 60; ++cp) { aq += T1q[u * 60 + cp] * wq[cp]; ak += T1k[u * 60 + cp] * wk[cp]; }
    qn[u] = aq; kn[u] = ak;
  }
  __syncthreads();
  if (t < 60) {
    float rq = 1.f / fmaxf(sqrtf(qn[t]), 1e-12f);
    float l[60], mx = -1e30f;
    for (int v = 0; v < 60; ++v) {
      float rk = 1.f / fmaxf(sqrtf(kn[v]), 1e-12f);
      l[v] = Gs[t * 60 + v] * rq * rk;
      mx = fmaxf(mx, l[v]);
    }
    float s = 0.f;
    for (int v = 0; v < 60; ++v) { l[v] = __expf(l[v] - mx); s += l[v]; }
    float rs = 1.f / s;
    for (int v = 0; v < 60; ++v) Fatt[t * 60 + v] = l[v] * rs;
  }
}

// ---------------- a_fea / f_fea -> CAT (bf16, per batch) ----------------
__global__ __launch_bounds__(256) void a_fea(const u16* __restrict__ PF,
    const float* __restrict__ Aatt, u16* __restrict__ CAT) {
  int hw = blockIdx.x * 256 + threadIdx.x;
  int dd = blockIdx.y;
  const u16* V = PF + ((size_t)(60 + dd)) * 230400 + hw;
  float v[25];
#pragma unroll
  for (int j = 0; j < 25; ++j) v[j] = b2f(V[(size_t)j * 9216]);
  u16* ob = CAT + (size_t)(1500 + dd * 25) * 9216 + hw;
  for (int i = 0; i < 25; ++i) {
    float a = 0.f;
#pragma unroll
    for (int j = 0; j < 25; ++j) a += Aatt[i * 25 + j] * v[j];
    ob[(size_t)i * 9216] = f2b(a);
  }
}

__global__ __launch_bounds__(256) void f_fea(const u16* __restrict__ PF,
    const float* __restrict__ Fatt, u16* __restrict__ CAT) {
  int s = blockIdx.x * 256 + threadIdx.x;
  const u16* V = PF + (size_t)120 * 230400 + s;
  float v[60];
#pragma unroll
  for (int u = 0; u < 60; ++u) v[u] = b2f(V[(size_t)u * 230400]);
  u16* ob = CAT + (size_t)27648000 + s;
  for (int u = 0; u < 60; ++u) {
    float a = 0.f;
#pragma unroll
    for (int vv = 0; vv < 60; ++vv) a += Fatt[u * 60 + vv] * v[vv];
    ob[(size_t)u * 230400] = f2b(a);
  }
}

// ---------------- precompute small weight products (once) ----------------
__global__ void precompute(const float* __restrict__ W1, const float* __restrict__ W2,
    const float* __restrict__ gamma, const float* __restrict__ beta,
    const float* __restrict__ Wang,
    float* __restrict__ Avec, float* __restrict__ Btvec,
    float* __restrict__ W1T, float* __restrict__ W2T,
    float* __restrict__ Ma, float* __restrict__ Mq, float* __restrict__ Mk) {
  int t = threadIdx.x;
  for (int e = t; e < 10800; e += 256) { int q = e / 60, j = e % 60; W1T[e] = W1[j * 180 + q]; }
  for (int e = t; e < 3600;  e += 256) { int j = e / 60, k = e % 60; W2T[e] = W2[k * 60 + j]; }
  for (int e = t; e < 3600; e += 256) {
    int c = e / 60, cp = e % 60;
    const float* Waq = Wang;            // rows 0..59
    const float* Wak = Wang + 3600;     // rows 60..119
    float ma = 0.f, mq = 0.f, mk = 0.f;
    for (int d = 0; d < 60; ++d) {
      float q = Waq[d * 60 + c], qp = Waq[d * 60 + cp];
      float k = Wak[d * 60 + c], kp = Wak[d * 60 + cp];
      ma += q * kp; mq += q * qp; mk += k * kp;
    }
    Ma[e] = ma; Mq[e] = mq; Mk[e] = mk;
  }
  if (t < 60) {
    float a = 0.f, bt = 0.f;
    for (int q = 0; q < 180; ++q) { a += gamma[q] * W1[t * 180 + q]; bt += beta[q] * W1[t * 180 + q]; }
    Avec[t] = a; Btvec[t] = bt;
  }
}

// ---------------- fused LayerNorm + MLP + residual (per batch) ----------------
__global__ __launch_bounds__(256) void fuse_ln_mlp(const u16* __restrict__ CAT,
    const float* __restrict__ xb, const float* __restrict__ gamma,
    const float* __restrict__ W1T, const float* __restrict__ W2T,
    const float* __restrict__ Avec, const float* __restrict__ Btvec,
    float* __restrict__ outb) {
  int s = blockIdx.x * 256 + threadIdx.x;
  const u16* cb = CAT + s;
  float S1[60];
#pragma unroll
  for (int j = 0; j < 60; ++j) S1[j] = 0.f;
  float sum = 0.f, sq = 0.f;
  for (int q = 0; q < 180; ++q) {
    float val = b2f(cb[(size_t)q * 230400]);
    sum += val; sq += val * val;
    float u = val * gamma[q];
    const float* w = W1T + q * 60;
#pragma unroll
    for (int j = 0; j < 60; ++j) S1[j] += u * w[j];
  }
  float mu = sum * (1.f / 180.f);
  float var = sq * (1.f / 180.f) - mu * mu;
  float inv = rsqrtf(var + 1e-5f);
  float y2[60];
#pragma unroll
  for (int k = 0; k < 60; ++k) y2[k] = 0.f;
  for (int j = 0; j < 60; ++j) {
    float y1 = inv * (S1[j] - mu * Avec[j]) + Btvec[j];
    y1 = fmaxf(y1, 0.f);
    const float* w = W2T + j * 60;
#pragma unroll
    for (int k = 0; k < 60; ++k) y2[k] += y1 * w[k];
  }
  const float* xs = xb + s;
  float* ob = outb + s;
#pragma unroll
  for (int k = 0; k < 60; ++k) ob[(size_t)k * 230400] = y2[k] + xs[(size_t)k * 230400];
}

// ---------------- launch ----------------
extern "C" void kernel_launch(void* const* d_in, const int* in_sizes, int n_in,
                              void* d_out, int out_size, void* d_ws, size_t ws_size,
                              hipStream_t stream) {
  const float* x        = (const float*)d_in[0];
  const float* w_spa_q  = (const float*)d_in[1];
  const float* w_spa_kv = (const float*)d_in[2];
  const float* w_ang    = (const float*)d_in[3];
  const float* w_fre    = (const float*)d_in[4];
  const float* ln_gamma = (const float*)d_in[5];
  const float* ln_beta  = (const float*)d_in[6];
  const float* w_mlp1   = (const float*)d_in[7];
  const float* w_mlp2   = (const float*)d_in[8];
  float* out = (float*)d_out;
  (void)in_sizes; (void)n_in; (void)out_size;

  // -------- workspace plan --------
  // Phase 0: Xb_all [0, 113,246,208) | Pg [113,246,208, 188,743,680)
  //          then G2_all [0, 37,748,736) (Xb dead), consumed by ang/fre before batch loop.
  // Batch loop regions:
  //   A1: PF_b | PS_b   A2: sqn+skn -> att   A3: partials -> L fp32 -> CAT bf16
  char* ws = (char*)d_ws;
  const size_t A1 = 0;
  const size_t A1_PS = 82944256;             // PF_b = 82,944,000 B
  const size_t A2 = 96934656;
  const size_t A3 = 139401984;
  size_t off = 224336640;                    // smalls
  auto alloc = [&](size_t bytes) -> void* {
    void* p = ws + off; off = (off + bytes + 255) & ~(size_t)255; return p;
  };
  float* Aatt  = (float*)alloc(4 * 625 * 4);
  float* Fatt  = (float*)alloc(4 * 3600 * 4);
  float* Adots = (float*)alloc(4 * 675 * 4);
  float* Gsg   = (float*)alloc(4 * 3600 * 4);
  float* Avec  = (float*)alloc(240);
  float* Btvec = (float*)alloc(240);
  float* W1T   = (float*)alloc(43200);
  float* W2T   = (float*)alloc(14400);
  float* Ma    = (float*)alloc(14400);
  float* Mq    = (float*)alloc(14400);
  float* Mk    = (float*)alloc(14400);

  if (off > ws_size) {  // graceful fallback: out = x (diagnosable, no fault)
    fallback_copy<<<4096, 256, 0, stream>>>(x, out, (size_t)55296000);
    return;
  }

  // phase-0 buffers
  u16*   XbAll = (u16*)(ws);                       // 4 x 28,311,552 B
  float* Pg    = (float*)(ws + 113246208);         // 8 x  9,437,184 B
  float* G2all = (float*)(ws);                     // 4 x  9,437,184 B (after Xb dead)

  // batch-loop buffers
  u16*   PF  = (u16*)(ws + A1);
  u16*   PS  = (u16*)(ws + A1_PS);
  u16*   sqn = (u16*)(ws + A2);              // 28,311,552 B
  u16*   skn = (u16*)(ws + A2 + 28311552);   //  7,077,888 B
  u16*   att = (u16*)(ws + A2);              // 42,467,328 B
  float* L   = (float*)(ws + A3);            // 84,934,656 B
  u16*   CAT = (u16*)(ws + A3);              // 82,944,000 B
  float* Pbig   = (float*)(ws + A3);             // 25*9216*4
  float* Psmall = (float*)(ws + A3 + 921600);    // 25*2304*4

  precompute<<<1, 256, 0, stream>>>(w_mlp1, w_mlp2, ln_gamma, ln_beta, w_ang,
                                    Avec, Btvec, W1T, W2T, Ma, Mq, Mk);

  // ---- phase 0: all-batch Gram (upper triangle) + angular/frequency attention ----
  for (int b = 0; b < 4; ++b)
    cast_x<<<13824, 256, 0, stream>>>(x + (size_t)b * 13824000, XbAll + (size_t)b * 14155776);
  gram_gemm<<<dim3(78, 1, 8), 256, 0, stream>>>(XbAll, Pg);
  reduce_mirror<<<dim3(300, 4), 256, 0, stream>>>(Pg, G2all);
  ang_dots<<<dim3(675, 4), 256, 0, stream>>>(G2all, Ma, Mq, Mk, Adots);
  ang_finish<<<4, 64, 0, stream>>>(Adots, Aatt);
  fre_gs<<<dim3(15, 4), 256, 0, stream>>>(G2all, Gsg);
  fre_finish<<<4, 256, 0, stream>>>(Gsg, w_fre, Fatt);

  // ---- per-batch spatial pipeline ----
  for (int b = 0; b < 4; ++b) {
    const float* xb = x + (size_t)b * 13824000;
    float* outb = out + (size_t)b * 13824000;

    // --- projections (PF overwrites G2all space; G2all already consumed) ---
    proj_full<<<dim3(900, 3), 256, 0, stream>>>(xb, w_spa_q, w_ang, w_fre, PF);
    proj_sub<<<dim3(225, 4), 256, 0, stream>>>(xb, w_spa_kv, PS);

    // --- spatial attention normalize+transpose (grid-parallel 2-pass) ---
    norm_sums<<<dim3(36, 25), 256, 0, stream>>>(PF, Pbig, 9216);
    transpose_scale<<<dim3(144, 24), 256, 0, stream>>>(PF, Pbig, sqn, 9216);
    norm_sums<<<dim3(9, 25), 256, 0, stream>>>(PS, Psmall, 2304);
    transpose_scale<<<dim3(36, 24), 256, 0, stream>>>(PS, Psmall, skn, 2304);

    // --- spatial attention ---
    gemm_bt<9216, 2304, 1536, 0><<<dim3(72, 18), 256, 0, stream>>>(sqn, skn, L);
    softmax_rows<<<9216, 256, 0, stream>>>(L, att);   // att overwrites sqn/skn (dead)
    gemm_bt<9216, 1536, 2304, 2><<<dim3(72, 12), 256, 0, stream>>>(att, PS + 3456000, CAT);

    // --- small attention features ---
    a_fea<<<dim3(36, 60), 256, 0, stream>>>(PF, Aatt + b * 625, CAT);
    f_fea<<<900, 256, 0, stream>>>(PF, Fatt + b * 3600, CAT);

    // --- LN + MLP + residual ---
    fuse_ln_mlp<<<900, 256, 0, stream>>>(CAT, xb, ln_gamma, W1T, W2T, Avec, Btvec, outb);
  }
}